// Round 1
// baseline (331.419 us; speedup 1.0000x reference)
//
#include <hip/hip_runtime.h>
#include <math.h>

#define CC 128      // channels (FIN=HID=OUT)
#define KC 32       // K chunk for GEMM staging
#define TNODES 32   // nodes per GEMM block
#define MROWS 64    // 2 batches * TNODES

// ---------------- CSR build ----------------

__global__ __launch_bounds__(256) void k_zero_i32(int* __restrict__ p, int n) {
    int i = blockIdx.x * 256 + threadIdx.x;
    if (i < n) p[i] = 0;
}

__global__ __launch_bounds__(256) void k_hist(const int* __restrict__ row, int* __restrict__ cnt, int E) {
    int e = blockIdx.x * 256 + threadIdx.x;
    if (e < E) atomicAdd(&cnt[row[e]], 1);
}

__device__ __forceinline__ int wave_incl_scan(int v) {
    #pragma unroll
    for (int d = 1; d < 64; d <<= 1) {
        int t = __shfl_up(v, d);
        if ((threadIdx.x & 63) >= d) v += t;
    }
    return v;
}

// per-1024-element block sums
__global__ __launch_bounds__(256) void k_scan_a(const int* __restrict__ cnt, int* __restrict__ bsum, int N) {
    int base = blockIdx.x * 1024 + threadIdx.x * 4;
    int s = 0;
    #pragma unroll
    for (int u = 0; u < 4; ++u) { int i = base + u; if (i < N) s += cnt[i]; }
    #pragma unroll
    for (int d = 32; d > 0; d >>= 1) s += __shfl_down(s, d);
    __shared__ int wsum[4];
    if ((threadIdx.x & 63) == 0) wsum[threadIdx.x >> 6] = s;
    __syncthreads();
    if (threadIdx.x == 0) bsum[blockIdx.x] = wsum[0] + wsum[1] + wsum[2] + wsum[3];
}

// exclusive scan of block sums (single wave, chunked with carry)
__global__ __launch_bounds__(64) void k_scan_b(const int* __restrict__ bsum, int* __restrict__ boff,
                                               int* __restrict__ off, int N, int nb) {
    int carry = 0;
    for (int base = 0; base < nb; base += 64) {
        int t = base + (int)threadIdx.x;
        int v = (t < nb) ? bsum[t] : 0;
        int incl = wave_incl_scan(v);
        if (t < nb) boff[t] = carry + incl - v;
        carry += __shfl(incl, 63);
    }
    if (threadIdx.x == 0) off[N] = carry;
}

// local scan + global offset -> off[i]
__global__ __launch_bounds__(256) void k_scan_c(const int* __restrict__ cnt, const int* __restrict__ boff,
                                                int* __restrict__ off, int N) {
    int t = threadIdx.x;
    int base = blockIdx.x * 1024 + t * 4;
    int v[4]; int s = 0;
    #pragma unroll
    for (int u = 0; u < 4; ++u) { int i = base + u; v[u] = (i < N) ? cnt[i] : 0; s += v[u]; }
    int incl = wave_incl_scan(s);
    __shared__ int wsum[4];
    int w = t >> 6, lane = t & 63;
    if (lane == 63) wsum[w] = incl;
    __syncthreads();
    int run = incl - s + boff[blockIdx.x];
    for (int ww = 0; ww < w; ++ww) run += wsum[ww];
    #pragma unroll
    for (int u = 0; u < 4; ++u) { int i = base + u; if (i < N) off[i] = run; run += v[u]; }
}

__global__ __launch_bounds__(256) void k_fill(const int* __restrict__ row, const int* __restrict__ col,
                                              const float* __restrict__ nrm, const int* __restrict__ off,
                                              int* __restrict__ cur, int* __restrict__ colS,
                                              float* __restrict__ wS, int E) {
    int e = blockIdx.x * 256 + threadIdx.x;
    if (e < E) {
        int r = row[e];
        int p = off[r] + atomicAdd(&cur[r], 1);
        colS[p] = col[e];
        wS[p] = nrm[e];
    }
}

// ---------------- fused GEMM + BatchNorm + GELU ----------------
// h[b,n,o] = sum_k X[b,n,k]*W[o,k] + bias[o]; BN per node over (b,o); exact-erf GELU.
// Tile: 32 nodes -> 64 M-rows (m<32: batch0, else batch1) x 128 cols, K in chunks of 32.
// 256 threads: tx=tid&15 -> cols 8*tx..8*tx+7 ; ty=tid>>4 -> rows 4*ty..4*ty+3.
__global__ __launch_bounds__(256) void k_gemm_bn_gelu(
    const float* __restrict__ X, const float* __restrict__ W,
    const float* __restrict__ bias, const float* __restrict__ gamma, const float* __restrict__ beta,
    float* __restrict__ Out, int N)
{
    __shared__ float Xs[MROWS][KC + 4];   // +4 pad keeps float4 alignment, breaks bank stride
    __shared__ float Ws[KC][CC + 4];      // transposed W chunk: Ws[k][o]
    __shared__ float RS[MROWS][17];
    __shared__ float RQ[MROWS][17];
    __shared__ float SCv[TNODES], SHv[TNODES];

    const int tid = threadIdx.x;
    const int tx = tid & 15;
    const int ty = tid >> 4;
    const int n0 = blockIdx.x * TNODES;

    float acc[4][8];
    #pragma unroll
    for (int i = 0; i < 4; ++i)
        #pragma unroll
        for (int j = 0; j < 8; ++j) acc[i][j] = 0.f;

    for (int kc = 0; kc < CC; kc += KC) {
        // stage X: 64 rows x 32 k = 512 float4, 2 per thread, coalesced
        #pragma unroll
        for (int h = 0; h < 2; ++h) {
            int f = tid + h * 256;
            int m = f >> 3;
            int l4 = f & 7;
            int nn = (m < TNODES) ? m : m - TNODES;
            int b  = (m < TNODES) ? 0 : 1;
            int node = n0 + nn;
            float4 v = make_float4(0.f, 0.f, 0.f, 0.f);
            if (node < N)
                v = *(const float4*)&X[(size_t)b * N * CC + (size_t)node * CC + kc + l4 * 4];
            *(float4*)&Xs[m][l4 * 4] = v;
        }
        // stage W transposed: Ws[kk][o] = W[o][kc+kk]
        {
            int o  = tid >> 1;
            int kq = tid & 1;
            #pragma unroll
            for (int u = 0; u < 4; ++u) {
                float4 v = *(const float4*)&W[(size_t)o * CC + kc + kq * 16 + u * 4];
                int kk = kq * 16 + u * 4;
                Ws[kk + 0][o] = v.x;
                Ws[kk + 1][o] = v.y;
                Ws[kk + 2][o] = v.z;
                Ws[kk + 3][o] = v.w;
            }
        }
        __syncthreads();
        #pragma unroll
        for (int k = 0; k < KC; ++k) {
            float xr[4];
            #pragma unroll
            for (int i = 0; i < 4; ++i) xr[i] = Xs[ty * 4 + i][k];
            const float4 wa = *(const float4*)&Ws[k][tx * 8];
            const float4 wb = *(const float4*)&Ws[k][tx * 8 + 4];
            float wv[8] = {wa.x, wa.y, wa.z, wa.w, wb.x, wb.y, wb.z, wb.w};
            #pragma unroll
            for (int i = 0; i < 4; ++i)
                #pragma unroll
                for (int j = 0; j < 8; ++j)
                    acc[i][j] = fmaf(xr[i], wv[j], acc[i][j]);
        }
        __syncthreads();
    }

    // + bias (before BN stats, as in reference)
    float bb[8];
    #pragma unroll
    for (int j = 0; j < 8; ++j) bb[j] = bias[tx * 8 + j];
    #pragma unroll
    for (int i = 0; i < 4; ++i)
        #pragma unroll
        for (int j = 0; j < 8; ++j) acc[i][j] += bb[j];

    // BN stats: per node over both batch rows (256 values)
    #pragma unroll
    for (int i = 0; i < 4; ++i) {
        float rs = 0.f, rq = 0.f;
        #pragma unroll
        for (int j = 0; j < 8; ++j) { rs += acc[i][j]; rq += acc[i][j] * acc[i][j]; }
        RS[ty * 4 + i][tx] = rs;
        RQ[ty * 4 + i][tx] = rq;
    }
    __syncthreads();
    if (tid < TNODES) {
        float s = 0.f, q = 0.f;
        #pragma unroll
        for (int t = 0; t < 16; ++t) {
            s += RS[tid][t] + RS[tid + TNODES][t];
            q += RQ[tid][t] + RQ[tid + TNODES][t];
        }
        float mean = s * (1.f / 256.f);
        float var  = q * (1.f / 256.f) - mean * mean;   // biased, torch-style
        int node = n0 + tid;
        float gam = (node < N) ? gamma[node] : 1.f;
        float bet = (node < N) ? beta[node]  : 0.f;
        float inv = rsqrtf(fmaxf(var, 0.f) + 1e-5f);
        float sc = gam * inv;
        SCv[tid] = sc;
        SHv[tid] = bet - mean * sc;
    }
    __syncthreads();

    #pragma unroll
    for (int i = 0; i < 4; ++i) {
        int m = ty * 4 + i;
        int nn = (m < TNODES) ? m : m - TNODES;
        int b  = (m < TNODES) ? 0 : 1;
        int node = n0 + nn;
        if (node < N) {
            float sc = SCv[nn], sh = SHv[nn];
            float o[8];
            #pragma unroll
            for (int j = 0; j < 8; ++j) {
                float y = acc[i][j] * sc + sh;
                o[j] = 0.5f * y * (1.f + erff(y * 0.70710678118654752f));  // exact GELU
            }
            float* dst = &Out[(size_t)b * N * CC + (size_t)node * CC + tx * 8];
            *(float4*)&dst[0] = make_float4(o[0], o[1], o[2], o[3]);
            *(float4*)&dst[4] = make_float4(o[4], o[5], o[6], o[7]);
        }
    }
}

// ---------------- per-dst aggregation (no atomics) ----------------
// Out[b,n,c] = sum_{j in CSR[n]} wS[j] * A[b, colS[j], c]
__global__ __launch_bounds__(128) void k_aggregate(
    const float* __restrict__ A, const int* __restrict__ off,
    const int* __restrict__ colS, const float* __restrict__ wS,
    float* __restrict__ Out, int N)
{
    int n = blockIdx.x;
    int c = threadIdx.x;
    int s = off[n], e = off[n + 1];
    const float* A1 = A + (size_t)N * CC;
    float a0 = 0.f, a1 = 0.f;
    for (int j = s; j < e; ++j) {
        int cs = colS[j];
        float w = wS[j];
        a0 = fmaf(w, A[(size_t)cs * CC + c], a0);
        a1 = fmaf(w, A1[(size_t)cs * CC + c], a1);
    }
    Out[(size_t)n * CC + c] = a0;
    Out[(size_t)N * CC + (size_t)n * CC + c] = a1;
}

// ---------------- launch ----------------

extern "C" void kernel_launch(void* const* d_in, const int* in_sizes, int n_in,
                              void* d_out, int out_size, void* d_ws, size_t ws_size,
                              hipStream_t stream)
{
    const float* x   = (const float*)d_in[0];
    const int*   ei  = (const int*)d_in[1];
    const float* nrm = (const float*)d_in[2];
    const float* W1  = (const float*)d_in[3];
    const float* b1  = (const float*)d_in[4];
    const float* g1  = (const float*)d_in[5];
    const float* be1 = (const float*)d_in[6];
    const float* W2  = (const float*)d_in[7];
    const float* b2  = (const float*)d_in[8];
    const float* g2  = (const float*)d_in[9];
    const float* be2 = (const float*)d_in[10];

    const int N = in_sizes[5];   // g1 has N elements
    const int E = in_sizes[2];   // norm has E elements
    const int* row = ei;         // edge_index[0] = scatter dst
    const int* col = ei + E;     // edge_index[1] = gather src
    const int nb = (N + 1023) / 1024;

    auto al = [](size_t v) { return (v + 255) & ~(size_t)255; };
    char* p = (char*)d_ws;
    int* off    = (int*)p;   p += al((size_t)(N + 1) * 4);
    int* cur    = (int*)p;   p += al((size_t)N * 4);
    int* colS   = (int*)p;   p += al((size_t)E * 4);
    float* wS   = (float*)p; p += al((size_t)E * 4);
    int* bsum   = (int*)p;   p += al((size_t)nb * 4);
    int* boff   = (int*)p;   p += al((size_t)nb * 4);
    float* bufA = (float*)p; p += al((size_t)2 * N * CC * 4);
    float* out  = (float*)d_out;

    // CSR by destination (rebuilt every call; deterministic work)
    k_zero_i32<<<(N + 255) / 256, 256, 0, stream>>>(cur, N);
    k_hist<<<(E + 255) / 256, 256, 0, stream>>>(row, cur, E);
    k_scan_a<<<nb, 256, 0, stream>>>(cur, bsum, N);
    k_scan_b<<<1, 64, 0, stream>>>(bsum, boff, off, N, nb);
    k_scan_c<<<nb, 256, 0, stream>>>(cur, boff, off, N);
    k_zero_i32<<<(N + 255) / 256, 256, 0, stream>>>(cur, N);
    k_fill<<<(E + 255) / 256, 256, 0, stream>>>(row, col, nrm, off, cur, colS, wS, E);

    const int gb = (N + TNODES - 1) / TNODES;
    // layer 1
    k_gemm_bn_gelu<<<gb, 256, 0, stream>>>(x, W1, b1, g1, be1, bufA, N);
    k_aggregate<<<N, 128, 0, stream>>>(bufA, off, colS, wS, out, N);
    // layer 2 (reads d_out as input, ping-pong)
    k_gemm_bn_gelu<<<gb, 256, 0, stream>>>(out, W2, b2, g2, be2, bufA, N);
    k_aggregate<<<N, 128, 0, stream>>>(bufA, off, colS, wS, out, N);
}

// Round 2
// 263.074 us; speedup vs baseline: 1.2598x; 1.2598x over previous
//
#include <hip/hip_runtime.h>
#include <math.h>

#define CC 128      // channels (FIN=HID=OUT)
#define TNODES 32   // nodes per GEMM block (64 M-rows = 32 nodes x 2 batches)

typedef unsigned short u16;
typedef short bf16x8 __attribute__((ext_vector_type(8)));
typedef float f32x4 __attribute__((ext_vector_type(4)));

__device__ __forceinline__ u16 f2bf(float f) {
    union { float f; unsigned u; } v; v.f = f;
    unsigned u = v.u;
    return (u16)((u + 0x7FFFu + ((u >> 16) & 1u)) >> 16);   // RNE
}
__device__ __forceinline__ float bf2f(unsigned hi16) {
    union { unsigned u; float f; } v; v.u = hi16 << 16; return v.f;
}

// ---------------- CSR build ----------------

__global__ __launch_bounds__(256) void k_zero_i32(int* __restrict__ p, int n) {
    int i = blockIdx.x * 256 + threadIdx.x;
    if (i < n) p[i] = 0;
}

__global__ __launch_bounds__(256) void k_hist(const int* __restrict__ row, int* __restrict__ cnt, int E) {
    int e = blockIdx.x * 256 + threadIdx.x;
    if (e < E) atomicAdd(&cnt[row[e]], 1);
}

__device__ __forceinline__ int wave_incl_scan(int v) {
    #pragma unroll
    for (int d = 1; d < 64; d <<= 1) {
        int t = __shfl_up(v, d);
        if ((threadIdx.x & 63) >= d) v += t;
    }
    return v;
}

__global__ __launch_bounds__(256) void k_scan_a(const int* __restrict__ cnt, int* __restrict__ bsum, int N) {
    int base = blockIdx.x * 1024 + threadIdx.x * 4;
    int s = 0;
    #pragma unroll
    for (int u = 0; u < 4; ++u) { int i = base + u; if (i < N) s += cnt[i]; }
    #pragma unroll
    for (int d = 32; d > 0; d >>= 1) s += __shfl_down(s, d);
    __shared__ int wsum[4];
    if ((threadIdx.x & 63) == 0) wsum[threadIdx.x >> 6] = s;
    __syncthreads();
    if (threadIdx.x == 0) bsum[blockIdx.x] = wsum[0] + wsum[1] + wsum[2] + wsum[3];
}

__global__ __launch_bounds__(64) void k_scan_b(const int* __restrict__ bsum, int* __restrict__ boff,
                                               int* __restrict__ off, int N, int nb) {
    int carry = 0;
    for (int base = 0; base < nb; base += 64) {
        int t = base + (int)threadIdx.x;
        int v = (t < nb) ? bsum[t] : 0;
        int incl = wave_incl_scan(v);
        if (t < nb) boff[t] = carry + incl - v;
        carry += __shfl(incl, 63);
    }
    if (threadIdx.x == 0) off[N] = carry;
}

__global__ __launch_bounds__(256) void k_scan_c(const int* __restrict__ cnt, const int* __restrict__ boff,
                                                int* __restrict__ off, int N) {
    int t = threadIdx.x;
    int base = blockIdx.x * 1024 + t * 4;
    int v[4]; int s = 0;
    #pragma unroll
    for (int u = 0; u < 4; ++u) { int i = base + u; v[u] = (i < N) ? cnt[i] : 0; s += v[u]; }
    int incl = wave_incl_scan(s);
    __shared__ int wsum[4];
    int w = t >> 6, lane = t & 63;
    if (lane == 63) wsum[w] = incl;
    __syncthreads();
    int run = incl - s + boff[blockIdx.x];
    for (int ww = 0; ww < w; ++ww) run += wsum[ww];
    #pragma unroll
    for (int u = 0; u < 4; ++u) { int i = base + u; if (i < N) off[i] = run; run += v[u]; }
}

__global__ __launch_bounds__(256) void k_fill(const int* __restrict__ row, const int* __restrict__ col,
                                              const float* __restrict__ nrm, const int* __restrict__ off,
                                              int* __restrict__ cur, int* __restrict__ colS,
                                              float* __restrict__ wS, int E) {
    int e = blockIdx.x * 256 + threadIdx.x;
    if (e < E) {
        int r = row[e];
        int p = off[r] + atomicAdd(&cur[r], 1);
        colS[p] = col[e];
        wS[p] = nrm[e];
    }
}

// ---------------- W -> bf16 ----------------
__global__ __launch_bounds__(256) void k_w2bf(const float* __restrict__ W, u16* __restrict__ Wb, int n) {
    int i = blockIdx.x * 256 + threadIdx.x;
    if (i < n) Wb[i] = f2bf(W[i]);
}

// ---------------- fused MFMA GEMM + BatchNorm + GELU ----------------
// h[b,n,o] = sum_k X[b,n,k]*W[o,k] + bias[o]; BN per node over (b,o); exact-erf GELU.
// Block: 256 thr = 4 waves. Tile 64 M-rows (m<32: batch0 node n0+m; m>=32: batch1) x 128 cols.
// Wave w owns rows 16w..16w+15. MFMA 16x16x32 bf16, K=128 in 4 steps.
// A-frag: lane holds X[row=16w+(l&15)][32s + (l>>4)*8 .. +8]   (global, read once)
// B-frag: lane holds W[16t+(l&15)][32s + (l>>4)*8 .. +8]       (global bf16, L1-hot 32KB)
// C/D:    lane (g=l>>4,c=l&15) reg r -> D[16w+4g+r][16t+c]
template<int IN_BF16>
__global__ __launch_bounds__(256) void k_gemm_bn_gelu(
    const void* __restrict__ Xv, const u16* __restrict__ Wb,
    const float* __restrict__ bias, const float* __restrict__ gamma, const float* __restrict__ beta,
    u16* __restrict__ Out, int N)
{
    __shared__ float rowS[64], rowQ[64], SCv[TNODES], SHv[TNODES];

    const int tid = threadIdx.x;
    const int w = tid >> 6;
    const int l = tid & 63;
    const int g = l >> 4;
    const int c = l & 15;
    const int n0 = blockIdx.x * TNODES;

    // ---- A fragments: row for loading = 16w + c ----
    const int am = w * 16 + c;
    const int ab = am >> 5;
    const int an = n0 + (am & 31);
    const bool avalid = an < N;

    bf16x8 af[4];
    if (IN_BF16) {
        const u16* X = (const u16*)Xv;
        const u16* base = X + ((size_t)ab * N + an) * CC + g * 8;
        #pragma unroll
        for (int s = 0; s < 4; ++s) {
            bf16x8 v = {0, 0, 0, 0, 0, 0, 0, 0};
            if (avalid) v = *(const bf16x8*)(base + s * 32);
            af[s] = v;
        }
    } else {
        const float* X = (const float*)Xv;
        const float* base = X + ((size_t)ab * N + an) * CC + g * 8;
        #pragma unroll
        for (int s = 0; s < 4; ++s) {
            float4 lo = make_float4(0.f, 0.f, 0.f, 0.f), hi = lo;
            if (avalid) {
                lo = *(const float4*)(base + s * 32);
                hi = *(const float4*)(base + s * 32 + 4);
            }
            bf16x8 v;
            v[0] = (short)f2bf(lo.x); v[1] = (short)f2bf(lo.y);
            v[2] = (short)f2bf(lo.z); v[3] = (short)f2bf(lo.w);
            v[4] = (short)f2bf(hi.x); v[5] = (short)f2bf(hi.y);
            v[6] = (short)f2bf(hi.z); v[7] = (short)f2bf(hi.w);
            af[s] = v;
        }
    }

    // ---- MFMA main loop ----
    f32x4 acc[8];
    #pragma unroll
    for (int t = 0; t < 8; ++t) acc[t] = (f32x4){0.f, 0.f, 0.f, 0.f};

    const u16* wbase = Wb + (size_t)(c * CC + g * 8);
    #pragma unroll
    for (int s = 0; s < 4; ++s) {
        bf16x8 bf[8];
        #pragma unroll
        for (int t = 0; t < 8; ++t)
            bf[t] = *(const bf16x8*)(wbase + (size_t)t * 16 * CC + s * 32);
        #pragma unroll
        for (int t = 0; t < 8; ++t)
            acc[t] = __builtin_amdgcn_mfma_f32_16x16x32_bf16(af[s], bf[t], acc[t], 0, 0, 0);
    }

    // ---- + bias, per-row stats (sum / sumsq over 128 cols) ----
    float bb[8];
    #pragma unroll
    for (int t = 0; t < 8; ++t) bb[t] = bias[t * 16 + c];

    float rs[4] = {0.f, 0.f, 0.f, 0.f}, rq[4] = {0.f, 0.f, 0.f, 0.f};
    #pragma unroll
    for (int t = 0; t < 8; ++t)
        #pragma unroll
        for (int r = 0; r < 4; ++r) {
            float h = acc[t][r] + bb[t];
            acc[t][r] = h;
            rs[r] += h;
            rq[r] += h * h;
        }
    #pragma unroll
    for (int d = 1; d < 16; d <<= 1) {
        #pragma unroll
        for (int r = 0; r < 4; ++r) {
            rs[r] += __shfl_xor(rs[r], d);
            rq[r] += __shfl_xor(rq[r], d);
        }
    }
    if (c == 0) {
        #pragma unroll
        for (int r = 0; r < 4; ++r) {
            rowS[w * 16 + g * 4 + r] = rs[r];
            rowQ[w * 16 + g * 4 + r] = rq[r];
        }
    }
    __syncthreads();

    if (tid < TNODES) {
        float s = rowS[tid] + rowS[tid + 32];
        float q = rowQ[tid] + rowQ[tid + 32];
        float mean = s * (1.f / 256.f);
        float var  = q * (1.f / 256.f) - mean * mean;   // biased, torch-style
        int node = n0 + tid;
        float gam = (node < N) ? gamma[node] : 1.f;
        float bet = (node < N) ? beta[node]  : 0.f;
        float sc = gam * rsqrtf(fmaxf(var, 0.f) + 1e-5f);
        SCv[tid] = sc;
        SHv[tid] = bet - mean * sc;
    }
    __syncthreads();

    // ---- BN + GELU + bf16 store ----
    #pragma unroll
    for (int r = 0; r < 4; ++r) {
        int dr = w * 16 + g * 4 + r;
        int dn = dr & 31, db = dr >> 5;
        int dnode = n0 + dn;
        if (dnode < N) {
            float sc = SCv[dn], sh = SHv[dn];
            u16* dst = Out + ((size_t)db * N + dnode) * CC + c;
            #pragma unroll
            for (int t = 0; t < 8; ++t) {
                float y = acc[t][r] * sc + sh;
                float o = 0.5f * y * (1.f + erff(y * 0.70710678118654752f));
                dst[t * 16] = f2bf(o);
            }
        }
    }
}

// ---------------- per-dst aggregation (no atomics) ----------------
// Out[b,n,c] = sum_j wS[j] * A[b, colS[j], c].  1 wave per node, lane = 2 channels.
template<int OUT_F32>
__global__ __launch_bounds__(256) void k_aggregate(
    const u16* __restrict__ A, const int* __restrict__ off,
    const int* __restrict__ colS, const float* __restrict__ wS,
    void* __restrict__ Outv, int N)
{
    int n = blockIdx.x * 4 + (threadIdx.x >> 6);
    if (n >= N) return;
    int l = threadIdx.x & 63;
    int s = off[n], e = off[n + 1];
    const u16* A1 = A + (size_t)N * CC;
    float a00 = 0.f, a01 = 0.f, a10 = 0.f, a11 = 0.f;
    for (int j = s; j < e; ++j) {
        int cs = colS[j];
        float wt = wS[j];
        unsigned v0 = *(const unsigned*)(A  + (size_t)cs * CC + 2 * l);
        unsigned v1 = *(const unsigned*)(A1 + (size_t)cs * CC + 2 * l);
        a00 = fmaf(wt, bf2f(v0 & 0xFFFFu), a00);
        a01 = fmaf(wt, bf2f(v0 >> 16),     a01);
        a10 = fmaf(wt, bf2f(v1 & 0xFFFFu), a10);
        a11 = fmaf(wt, bf2f(v1 >> 16),     a11);
    }
    if (OUT_F32) {
        float* Out = (float*)Outv;
        float* d0 = Out + (size_t)n * CC + 2 * l;
        float* d1 = Out + (size_t)N * CC + (size_t)n * CC + 2 * l;
        d0[0] = a00; d0[1] = a01;
        d1[0] = a10; d1[1] = a11;
    } else {
        u16* Out = (u16*)Outv;
        unsigned p0 = (unsigned)f2bf(a00) | ((unsigned)f2bf(a01) << 16);
        unsigned p1 = (unsigned)f2bf(a10) | ((unsigned)f2bf(a11) << 16);
        *(unsigned*)(Out + (size_t)n * CC + 2 * l) = p0;
        *(unsigned*)(Out + (size_t)N * CC + (size_t)n * CC + 2 * l) = p1;
    }
}

// ---------------- launch ----------------

extern "C" void kernel_launch(void* const* d_in, const int* in_sizes, int n_in,
                              void* d_out, int out_size, void* d_ws, size_t ws_size,
                              hipStream_t stream)
{
    const float* x   = (const float*)d_in[0];
    const int*   ei  = (const int*)d_in[1];
    const float* nrm = (const float*)d_in[2];
    const float* W1  = (const float*)d_in[3];
    const float* b1  = (const float*)d_in[4];
    const float* g1  = (const float*)d_in[5];
    const float* be1 = (const float*)d_in[6];
    const float* W2  = (const float*)d_in[7];
    const float* b2  = (const float*)d_in[8];
    const float* g2  = (const float*)d_in[9];
    const float* be2 = (const float*)d_in[10];

    const int N = in_sizes[5];   // g1 has N elements
    const int E = in_sizes[2];   // norm has E elements
    const int* row = ei;         // edge_index[0] = scatter dst
    const int* col = ei + E;     // edge_index[1] = gather src
    const int nb = (N + 1023) / 1024;

    auto al = [](size_t v) { return (v + 255) & ~(size_t)255; };
    char* p = (char*)d_ws;
    int* off    = (int*)p;   p += al((size_t)(N + 1) * 4);
    int* cur    = (int*)p;   p += al((size_t)N * 4);
    int* colS   = (int*)p;   p += al((size_t)E * 4);
    float* wS   = (float*)p; p += al((size_t)E * 4);
    int* bsum   = (int*)p;   p += al((size_t)nb * 4);
    int* boff   = (int*)p;   p += al((size_t)nb * 4);
    u16* Wb1    = (u16*)p;   p += al((size_t)CC * CC * 2);
    u16* Wb2    = (u16*)p;   p += al((size_t)CC * CC * 2);
    u16* bufA   = (u16*)p;   p += al((size_t)2 * N * CC * 2);
    u16* bufB   = (u16*)p;   p += al((size_t)2 * N * CC * 2);

    // CSR by destination (rebuilt every call; deterministic work)
    k_zero_i32<<<(N + 255) / 256, 256, 0, stream>>>(cur, N);
    k_hist<<<(E + 255) / 256, 256, 0, stream>>>(row, cur, E);
    k_scan_a<<<nb, 256, 0, stream>>>(cur, bsum, N);
    k_scan_b<<<1, 64, 0, stream>>>(bsum, boff, off, N, nb);
    k_scan_c<<<nb, 256, 0, stream>>>(cur, boff, off, N);
    k_zero_i32<<<(N + 255) / 256, 256, 0, stream>>>(cur, N);
    k_fill<<<(E + 255) / 256, 256, 0, stream>>>(row, col, nrm, off, cur, colS, wS, E);

    // W -> bf16 (tiny)
    k_w2bf<<<(CC * CC + 255) / 256, 256, 0, stream>>>(W1, Wb1, CC * CC);
    k_w2bf<<<(CC * CC + 255) / 256, 256, 0, stream>>>(W2, Wb2, CC * CC);

    const int gb = (N + TNODES - 1) / TNODES;
    const int ga = (N + 3) / 4;
    // layer 1
    k_gemm_bn_gelu<0><<<gb, 256, 0, stream>>>(x, Wb1, b1, g1, be1, bufA, N);
    k_aggregate<0><<<ga, 256, 0, stream>>>(bufA, off, colS, wS, bufB, N);
    // layer 2
    k_gemm_bn_gelu<1><<<gb, 256, 0, stream>>>(bufB, Wb2, b2, g2, be2, bufA, N);
    k_aggregate<1><<<ga, 256, 0, stream>>>(bufA, off, colS, wS, (float*)d_out, N);
}

// Round 3
// 234.969 us; speedup vs baseline: 1.4105x; 1.1196x over previous
//
#include <hip/hip_runtime.h>
#include <math.h>

#define CC 128      // channels (FIN=HID=OUT)
#define TNODES 32   // nodes per GEMM block (64 M-rows = 32 nodes x 2 batches)
#define TPAD 132    // LDS transpose row stride (u16): 264B -> 2-way-free banks, 8B-aligned

typedef unsigned short u16;
typedef short bf16x8 __attribute__((ext_vector_type(8)));
typedef short bf16x4 __attribute__((ext_vector_type(4)));
typedef float f32x4 __attribute__((ext_vector_type(4)));

__device__ __forceinline__ u16 f2bf(float f) {
    union { float f; unsigned u; } v; v.f = f;
    unsigned u = v.u;
    return (u16)((u + 0x7FFFu + ((u >> 16) & 1u)) >> 16);   // RNE
}
__device__ __forceinline__ float bf2f(unsigned hi16) {
    union { unsigned u; float f; } v; v.u = hi16 << 16; return v.f;
}

// ---------------- CSR build ----------------

__global__ __launch_bounds__(256) void k_zero_i32(int* __restrict__ p, int n) {
    int i = blockIdx.x * 256 + threadIdx.x;
    if (i < n) p[i] = 0;
}

__global__ __launch_bounds__(256) void k_hist(const int* __restrict__ row, int* __restrict__ cnt, int E) {
    int e = blockIdx.x * 256 + threadIdx.x;
    if (e < E) atomicAdd(&cnt[row[e]], 1);
}

__device__ __forceinline__ int wave_incl_scan(int v) {
    #pragma unroll
    for (int d = 1; d < 64; d <<= 1) {
        int t = __shfl_up(v, d);
        if ((threadIdx.x & 63) >= d) v += t;
    }
    return v;
}

__global__ __launch_bounds__(256) void k_scan_a(const int* __restrict__ cnt, int* __restrict__ bsum, int N) {
    int base = blockIdx.x * 1024 + threadIdx.x * 4;
    int s = 0;
    #pragma unroll
    for (int u = 0; u < 4; ++u) { int i = base + u; if (i < N) s += cnt[i]; }
    #pragma unroll
    for (int d = 32; d > 0; d >>= 1) s += __shfl_down(s, d);
    __shared__ int wsum[4];
    if ((threadIdx.x & 63) == 0) wsum[threadIdx.x >> 6] = s;
    __syncthreads();
    if (threadIdx.x == 0) bsum[blockIdx.x] = wsum[0] + wsum[1] + wsum[2] + wsum[3];
}

__global__ __launch_bounds__(64) void k_scan_b(const int* __restrict__ bsum, int* __restrict__ boff,
                                               int* __restrict__ off, int N, int nb) {
    int carry = 0;
    for (int base = 0; base < nb; base += 64) {
        int t = base + (int)threadIdx.x;
        int v = (t < nb) ? bsum[t] : 0;
        int incl = wave_incl_scan(v);
        if (t < nb) boff[t] = carry + incl - v;
        carry += __shfl(incl, 63);
    }
    if (threadIdx.x == 0) off[N] = carry;
}

__global__ __launch_bounds__(256) void k_scan_c(const int* __restrict__ cnt, const int* __restrict__ boff,
                                                int* __restrict__ off, int N) {
    int t = threadIdx.x;
    int base = blockIdx.x * 1024 + t * 4;
    int v[4]; int s = 0;
    #pragma unroll
    for (int u = 0; u < 4; ++u) { int i = base + u; v[u] = (i < N) ? cnt[i] : 0; s += v[u]; }
    int incl = wave_incl_scan(s);
    __shared__ int wsum[4];
    int w = t >> 6, lane = t & 63;
    if (lane == 63) wsum[w] = incl;
    __syncthreads();
    int run = incl - s + boff[blockIdx.x];
    for (int ww = 0; ww < w; ++ww) run += wsum[ww];
    #pragma unroll
    for (int u = 0; u < 4; ++u) { int i = base + u; if (i < N) off[i] = run; run += v[u]; }
}

__global__ __launch_bounds__(256) void k_fill(const int* __restrict__ row, const int* __restrict__ col,
                                              const float* __restrict__ nrm, const int* __restrict__ off,
                                              int* __restrict__ cur, int* __restrict__ colS,
                                              float* __restrict__ wS, int E) {
    int e = blockIdx.x * 256 + threadIdx.x;
    if (e < E) {
        int r = row[e];
        int p = off[r] + atomicAdd(&cur[r], 1);
        colS[p] = col[e];
        wS[p] = nrm[e];
    }
}

// ---------------- W -> bf16, repacked into MFMA B-fragment order ----------------
// Wp[((t*4+s)*64 + l)*8 + j] = bf16( W[16t + (l&15)][s*32 + (l>>4)*8 + j] )
// so a wave's B-frag load (for output tile t, K-step s) is 1KB contiguous.
__global__ __launch_bounds__(256) void k_wrepack(const float* __restrict__ W, u16* __restrict__ Wp) {
    int i = blockIdx.x * 256 + threadIdx.x;
    if (i < CC * CC) {
        int j = i & 7, l = (i >> 3) & 63, s = (i >> 9) & 3, t = i >> 11;
        int r = 16 * t + (l & 15);
        int k = s * 32 + (l >> 4) * 8 + j;
        Wp[i] = f2bf(W[r * CC + k]);
    }
}

// ---------------- fused MFMA GEMM + BatchNorm + GELU ----------------
// h[b,n,o] = sum_k X[b,n,k]*W[o,k] + bias[o]; BN per node over (b,o); exact-erf GELU.
// Block: 256 thr = 4 waves. Tile 64 M-rows (m<32: batch0 node n0+m; m>=32: batch1) x 128 cols.
// Wave w owns rows 16w..16w+15. MFMA 16x16x32 bf16, K=128 in 4 steps.
// C/D: lane (g=l>>4,c=l&15) reg r -> D[16w+4g+r][16t+c]; epilogue transposes via LDS
// to emit one coalesced 16B bf16 store per thread per row-chunk.
template<int IN_BF16>
__global__ __launch_bounds__(256) void k_gemm_bn_gelu(
    const void* __restrict__ Xv, const u16* __restrict__ Wp,
    const float* __restrict__ bias, const float* __restrict__ gamma, const float* __restrict__ beta,
    u16* __restrict__ Out, int N)
{
    __shared__ u16 T[64][TPAD];
    __shared__ float rowS[64], rowQ[64], SCv[TNODES], SHv[TNODES];

    const int tid = threadIdx.x;
    const int w = tid >> 6;
    const int l = tid & 63;
    const int g = l >> 4;
    const int c = l & 15;
    const int n0 = blockIdx.x * TNODES;

    // ---- A fragments: row for loading = 16w + c ----
    const int am = w * 16 + c;
    const int ab = am >> 5;
    const int an = n0 + (am & 31);
    const bool avalid = an < N;

    bf16x8 af[4];
    if (IN_BF16) {
        const u16* X = (const u16*)Xv;
        const u16* base = X + ((size_t)ab * N + an) * CC + g * 8;
        #pragma unroll
        for (int s = 0; s < 4; ++s) {
            bf16x8 v = {0, 0, 0, 0, 0, 0, 0, 0};
            if (avalid) v = *(const bf16x8*)(base + s * 32);
            af[s] = v;
        }
    } else {
        const float* X = (const float*)Xv;
        const float* base = X + ((size_t)ab * N + an) * CC + g * 8;
        #pragma unroll
        for (int s = 0; s < 4; ++s) {
            float4 lo = make_float4(0.f, 0.f, 0.f, 0.f), hi = lo;
            if (avalid) {
                lo = *(const float4*)(base + s * 32);
                hi = *(const float4*)(base + s * 32 + 4);
            }
            bf16x8 v;
            v[0] = (short)f2bf(lo.x); v[1] = (short)f2bf(lo.y);
            v[2] = (short)f2bf(lo.z); v[3] = (short)f2bf(lo.w);
            v[4] = (short)f2bf(hi.x); v[5] = (short)f2bf(hi.y);
            v[6] = (short)f2bf(hi.z); v[7] = (short)f2bf(hi.w);
            af[s] = v;
        }
    }

    // ---- MFMA main loop: B-frags are wave-contiguous 1KB loads from repacked Wp ----
    f32x4 acc[8];
    #pragma unroll
    for (int t = 0; t < 8; ++t) acc[t] = (f32x4){0.f, 0.f, 0.f, 0.f};

    #pragma unroll
    for (int s = 0; s < 4; ++s) {
        bf16x8 bf[8];
        #pragma unroll
        for (int t = 0; t < 8; ++t)
            bf[t] = *(const bf16x8*)(Wp + (((size_t)(t * 4 + s) * 64) + l) * 8);
        #pragma unroll
        for (int t = 0; t < 8; ++t)
            acc[t] = __builtin_amdgcn_mfma_f32_16x16x32_bf16(af[s], bf[t], acc[t], 0, 0, 0);
    }

    // ---- + bias, per-row stats (sum / sumsq over 128 cols) ----
    float bb[8];
    #pragma unroll
    for (int t = 0; t < 8; ++t) bb[t] = bias[t * 16 + c];

    float rs[4] = {0.f, 0.f, 0.f, 0.f}, rq[4] = {0.f, 0.f, 0.f, 0.f};
    #pragma unroll
    for (int t = 0; t < 8; ++t)
        #pragma unroll
        for (int r = 0; r < 4; ++r) {
            float h = acc[t][r] + bb[t];
            acc[t][r] = h;
            rs[r] += h;
            rq[r] += h * h;
        }
    #pragma unroll
    for (int d = 1; d < 16; d <<= 1) {
        #pragma unroll
        for (int r = 0; r < 4; ++r) {
            rs[r] += __shfl_xor(rs[r], d);
            rq[r] += __shfl_xor(rq[r], d);
        }
    }
    if (c == 0) {
        #pragma unroll
        for (int r = 0; r < 4; ++r) {
            rowS[w * 16 + g * 4 + r] = rs[r];
            rowQ[w * 16 + g * 4 + r] = rq[r];
        }
    }
    __syncthreads();

    if (tid < TNODES) {
        float s = rowS[tid] + rowS[tid + 32];
        float q = rowQ[tid] + rowQ[tid + 32];
        float mean = s * (1.f / 256.f);
        float var  = q * (1.f / 256.f) - mean * mean;   // biased, torch-style
        int node = n0 + tid;
        float gam = (node < N) ? gamma[node] : 1.f;
        float bet = (node < N) ? beta[node]  : 0.f;
        float sc = gam * rsqrtf(fmaxf(var, 0.f) + 1e-5f);
        SCv[tid] = sc;
        SHv[tid] = bet - mean * sc;
    }
    __syncthreads();

    // ---- BN + GELU -> bf16 into LDS (2-way-free banks via TPAD=132) ----
    #pragma unroll
    for (int r = 0; r < 4; ++r) {
        int dr = w * 16 + g * 4 + r;
        float sc = SCv[dr & 31], sh = SHv[dr & 31];
        #pragma unroll
        for (int t = 0; t < 8; ++t) {
            float y = acc[t][r] * sc + sh;
            float o = 0.5f * y * (1.f + erff(y * 0.70710678118654752f));
            T[dr][t * 16 + c] = f2bf(o);
        }
    }
    __syncthreads();

    // ---- coalesced store: each thread emits 16B per chunk, 4 chunks ----
    #pragma unroll
    for (int q = 0; q < 4; ++q) {
        int chunk = q * 256 + tid;
        int rowi = chunk >> 4;            // 0..63
        int offc = (chunk & 15) * 8;      // u16 offset, 16B-granular
        int dn = rowi & 31, db = rowi >> 5;
        int node = n0 + dn;
        if (node < N) {
            bf16x4 lo = *(const bf16x4*)&T[rowi][offc];
            bf16x4 hi = *(const bf16x4*)&T[rowi][offc + 4];
            bf16x8 v;
            v[0] = lo[0]; v[1] = lo[1]; v[2] = lo[2]; v[3] = lo[3];
            v[4] = hi[0]; v[5] = hi[1]; v[6] = hi[2]; v[7] = hi[3];
            *(bf16x8*)(Out + ((size_t)db * N + node) * CC + offc) = v;
        }
    }
}

// ---------------- per-dst aggregation (no atomics) ----------------
// Out[b,n,c] = sum_j wS[j] * A[b, colS[j], c].
// 1 wave per node: lane = (batch = l>>5, 4 channels = (l&31)*4). One 8B load per edge per lane.
template<int OUT_F32>
__global__ __launch_bounds__(256) void k_aggregate(
    const u16* __restrict__ A, const int* __restrict__ off,
    const int* __restrict__ colS, const float* __restrict__ wS,
    void* __restrict__ Outv, int N)
{
    int n = blockIdx.x * 4 + (threadIdx.x >> 6);
    if (n >= N) return;
    int l = threadIdx.x & 63;
    int b = l >> 5;
    int ch = (l & 31) * 4;
    const u16* Ab = A + (size_t)b * N * CC + ch;
    int s = off[n], e = off[n + 1];
    float a0 = 0.f, a1 = 0.f, a2 = 0.f, a3 = 0.f;
    for (int j = s; j < e; ++j) {
        int cs = colS[j];
        float wt = wS[j];
        bf16x4 v = *(const bf16x4*)(Ab + (size_t)cs * CC);
        a0 = fmaf(wt, bf2f((u16)v[0]), a0);
        a1 = fmaf(wt, bf2f((u16)v[1]), a1);
        a2 = fmaf(wt, bf2f((u16)v[2]), a2);
        a3 = fmaf(wt, bf2f((u16)v[3]), a3);
    }
    if (OUT_F32) {
        float* d = (float*)Outv + (size_t)b * N * CC + (size_t)n * CC + ch;
        d[0] = a0; d[1] = a1; d[2] = a2; d[3] = a3;
    } else {
        u16* d = (u16*)Outv + (size_t)b * N * CC + (size_t)n * CC + ch;
        bf16x4 v;
        v[0] = (short)f2bf(a0); v[1] = (short)f2bf(a1);
        v[2] = (short)f2bf(a2); v[3] = (short)f2bf(a3);
        *(bf16x4*)d = v;
    }
}

// ---------------- launch ----------------

extern "C" void kernel_launch(void* const* d_in, const int* in_sizes, int n_in,
                              void* d_out, int out_size, void* d_ws, size_t ws_size,
                              hipStream_t stream)
{
    const float* x   = (const float*)d_in[0];
    const int*   ei  = (const int*)d_in[1];
    const float* nrm = (const float*)d_in[2];
    const float* W1  = (const float*)d_in[3];
    const float* b1  = (const float*)d_in[4];
    const float* g1  = (const float*)d_in[5];
    const float* be1 = (const float*)d_in[6];
    const float* W2  = (const float*)d_in[7];
    const float* b2  = (const float*)d_in[8];
    const float* g2  = (const float*)d_in[9];
    const float* be2 = (const float*)d_in[10];

    const int N = in_sizes[5];   // g1 has N elements
    const int E = in_sizes[2];   // norm has E elements
    const int* row = ei;         // edge_index[0] = scatter dst
    const int* col = ei + E;     // edge_index[1] = gather src
    const int nb = (N + 1023) / 1024;

    auto al = [](size_t v) { return (v + 255) & ~(size_t)255; };
    char* p = (char*)d_ws;
    int* off    = (int*)p;   p += al((size_t)(N + 1) * 4);
    int* cur    = (int*)p;   p += al((size_t)N * 4);
    int* colS   = (int*)p;   p += al((size_t)E * 4);
    float* wS   = (float*)p; p += al((size_t)E * 4);
    int* bsum   = (int*)p;   p += al((size_t)nb * 4);
    int* boff   = (int*)p;   p += al((size_t)nb * 4);
    u16* Wp1    = (u16*)p;   p += al((size_t)CC * CC * 2);
    u16* Wp2    = (u16*)p;   p += al((size_t)CC * CC * 2);
    u16* bufA   = (u16*)p;   p += al((size_t)2 * N * CC * 2);
    u16* bufB   = (u16*)p;   p += al((size_t)2 * N * CC * 2);

    // CSR by destination (rebuilt every call; deterministic work)
    k_zero_i32<<<(N + 255) / 256, 256, 0, stream>>>(cur, N);
    k_hist<<<(E + 255) / 256, 256, 0, stream>>>(row, cur, E);
    k_scan_a<<<nb, 256, 0, stream>>>(cur, bsum, N);
    k_scan_b<<<1, 64, 0, stream>>>(bsum, boff, off, N, nb);
    k_scan_c<<<nb, 256, 0, stream>>>(cur, boff, off, N);
    k_zero_i32<<<(N + 255) / 256, 256, 0, stream>>>(cur, N);
    k_fill<<<(E + 255) / 256, 256, 0, stream>>>(row, col, nrm, off, cur, colS, wS, E);

    // W -> bf16 fragment-order repack (tiny)
    k_wrepack<<<(CC * CC + 255) / 256, 256, 0, stream>>>(W1, Wp1);
    k_wrepack<<<(CC * CC + 255) / 256, 256, 0, stream>>>(W2, Wp2);

    const int gb = (N + TNODES - 1) / TNODES;
    const int ga = (N + 3) / 4;
    // layer 1
    k_gemm_bn_gelu<0><<<gb, 256, 0, stream>>>(x, Wp1, b1, g1, be1, bufA, N);
    k_aggregate<0><<<ga, 256, 0, stream>>>(bufA, off, colS, wS, bufB, N);
    // layer 2
    k_gemm_bn_gelu<1><<<gb, 256, 0, stream>>>(bufB, Wp2, b2, g2, be2, bufA, N);
    k_aggregate<1><<<ga, 256, 0, stream>>>(bufA, off, colS, wS, (float*)d_out, N);
}

// Round 4
// 177.681 us; speedup vs baseline: 1.8653x; 1.3224x over previous
//
#include <hip/hip_runtime.h>
#include <math.h>

#define CC 128      // channels (FIN=HID=OUT)
#define TNODES 32   // nodes per GEMM block (64 M-rows = 32 nodes x 2 batches)
#define TPAD 132    // LDS transpose row stride (u16): 264B -> 2-way-free banks, 8B-aligned

typedef unsigned short u16;
typedef short bf16x8 __attribute__((ext_vector_type(8)));
typedef short bf16x4 __attribute__((ext_vector_type(4)));
typedef float f32x4 __attribute__((ext_vector_type(4)));

__device__ __forceinline__ u16 f2bf(float f) {
    union { float f; unsigned u; } v; v.f = f;
    unsigned u = v.u;
    return (u16)((u + 0x7FFFu + ((u >> 16) & 1u)) >> 16);   // RNE
}
__device__ __forceinline__ float bf2f(unsigned hi16) {
    union { unsigned u; float f; } v; v.u = hi16 << 16; return v.f;
}

// Exact-GELU via branch-free A&S 7.1.26 erf (|err| < 1.5e-7, far below bf16 noise).
// ~14 VALU ops + 1 rcp + 1 exp, no divergence (vs libm erff's ~90 with both branches).
__device__ __forceinline__ float gelu_f(float y) {
    float xa = fabsf(y) * 0.70710678118654752f;
    float t  = __builtin_amdgcn_rcpf(fmaf(0.3275911f, xa, 1.0f));
    float p  = fmaf(1.061405429f, t, -1.453152027f);
    p = fmaf(p, t, 1.421413741f);
    p = fmaf(p, t, -0.284496736f);
    p = fmaf(p, t, 0.254829592f);
    p *= t;
    float e  = __expf(-xa * xa);
    float er = fmaf(-p, e, 1.0f);          // erf(|x|)
    float s  = copysignf(er, y);
    return 0.5f * y * (1.0f + s);
}

// ---------------- CSR build ----------------

__global__ __launch_bounds__(256) void k_zero_i32(int* __restrict__ p, int n) {
    int i = blockIdx.x * 256 + threadIdx.x;
    if (i < n) p[i] = 0;
}

__global__ __launch_bounds__(256) void k_hist(const int* __restrict__ row, int* __restrict__ cnt, int E) {
    int e = blockIdx.x * 256 + threadIdx.x;
    if (e < E) atomicAdd(&cnt[row[e]], 1);
}

__device__ __forceinline__ int wave_incl_scan(int v) {
    #pragma unroll
    for (int d = 1; d < 64; d <<= 1) {
        int t = __shfl_up(v, d);
        if ((threadIdx.x & 63) >= d) v += t;
    }
    return v;
}

__global__ __launch_bounds__(256) void k_scan_a(const int* __restrict__ cnt, int* __restrict__ bsum, int N) {
    int base = blockIdx.x * 1024 + threadIdx.x * 4;
    int s = 0;
    #pragma unroll
    for (int u = 0; u < 4; ++u) { int i = base + u; if (i < N) s += cnt[i]; }
    #pragma unroll
    for (int d = 32; d > 0; d >>= 1) s += __shfl_down(s, d);
    __shared__ int wsum[4];
    if ((threadIdx.x & 63) == 0) wsum[threadIdx.x >> 6] = s;
    __syncthreads();
    if (threadIdx.x == 0) bsum[blockIdx.x] = wsum[0] + wsum[1] + wsum[2] + wsum[3];
}

__global__ __launch_bounds__(64) void k_scan_b(const int* __restrict__ bsum, int* __restrict__ boff,
                                               int* __restrict__ off, int N, int nb) {
    int carry = 0;
    for (int base = 0; base < nb; base += 64) {
        int t = base + (int)threadIdx.x;
        int v = (t < nb) ? bsum[t] : 0;
        int incl = wave_incl_scan(v);
        if (t < nb) boff[t] = carry + incl - v;
        carry += __shfl(incl, 63);
    }
    if (threadIdx.x == 0) off[N] = carry;
}

// local scan + global offset -> off[i]; also zeroes cnt for the subsequent k_fill
__global__ __launch_bounds__(256) void k_scan_c(int* __restrict__ cnt, const int* __restrict__ boff,
                                                int* __restrict__ off, int N) {
    int t = threadIdx.x;
    int base = blockIdx.x * 1024 + t * 4;
    int v[4]; int s = 0;
    #pragma unroll
    for (int u = 0; u < 4; ++u) { int i = base + u; v[u] = (i < N) ? cnt[i] : 0; s += v[u]; }
    int incl = wave_incl_scan(s);
    __shared__ int wsum[4];
    int w = t >> 6, lane = t & 63;
    if (lane == 63) wsum[w] = incl;
    __syncthreads();
    int run = incl - s + boff[blockIdx.x];
    for (int ww = 0; ww < w; ++ww) run += wsum[ww];
    #pragma unroll
    for (int u = 0; u < 4; ++u) {
        int i = base + u;
        if (i < N) { off[i] = run; cnt[i] = 0; }
        run += v[u];
    }
}

// packed edge list: .x = src col, .y = weight bits
__global__ __launch_bounds__(256) void k_fill(const int* __restrict__ row, const int* __restrict__ col,
                                              const float* __restrict__ nrm, const int* __restrict__ off,
                                              int* __restrict__ cur, int2* __restrict__ eg, int E) {
    int e = blockIdx.x * 256 + threadIdx.x;
    if (e < E) {
        int r = row[e];
        int p = off[r] + atomicAdd(&cur[r], 1);
        eg[p] = make_int2(col[e], __float_as_int(nrm[e]));
    }
}

// ---------------- W1,W2 -> bf16, repacked into MFMA B-fragment order ----------------
// Wp[((t*4+s)*64 + l)*8 + j] = bf16( W[16t + (l&15)][s*32 + (l>>4)*8 + j] )
__global__ __launch_bounds__(256) void k_wrepack(const float* __restrict__ W1, u16* __restrict__ Wp1,
                                                 const float* __restrict__ W2, u16* __restrict__ Wp2) {
    int i = blockIdx.x * 256 + threadIdx.x;
    const float* W = (i < CC * CC) ? W1 : W2;
    u16* Wp = (i < CC * CC) ? Wp1 : Wp2;
    int ii = (i < CC * CC) ? i : i - CC * CC;
    if (ii < CC * CC) {
        int j = ii & 7, l = (ii >> 3) & 63, s = (ii >> 9) & 3, t = ii >> 11;
        int r = 16 * t + (l & 15);
        int k = s * 32 + (l >> 4) * 8 + j;
        Wp[ii] = f2bf(W[r * CC + k]);
    }
}

// ---------------- fused MFMA GEMM + BatchNorm + GELU ----------------
template<int IN_BF16>
__global__ __launch_bounds__(256) void k_gemm_bn_gelu(
    const void* __restrict__ Xv, const u16* __restrict__ Wp,
    const float* __restrict__ bias, const float* __restrict__ gamma, const float* __restrict__ beta,
    u16* __restrict__ Out, int N)
{
    __shared__ u16 T[64][TPAD];
    __shared__ float rowS[64], rowQ[64], SCv[TNODES], SHv[TNODES];

    const int tid = threadIdx.x;
    const int w = tid >> 6;
    const int l = tid & 63;
    const int g = l >> 4;
    const int c = l & 15;
    const int n0 = blockIdx.x * TNODES;

    // ---- A fragments: row for loading = 16w + c ----
    const int am = w * 16 + c;
    const int ab = am >> 5;
    const int an = n0 + (am & 31);
    const bool avalid = an < N;

    bf16x8 af[4];
    if (IN_BF16) {
        const u16* X = (const u16*)Xv;
        const u16* base = X + ((size_t)ab * N + an) * CC + g * 8;
        #pragma unroll
        for (int s = 0; s < 4; ++s) {
            bf16x8 v = {0, 0, 0, 0, 0, 0, 0, 0};
            if (avalid) v = *(const bf16x8*)(base + s * 32);
            af[s] = v;
        }
    } else {
        const float* X = (const float*)Xv;
        const float* base = X + ((size_t)ab * N + an) * CC + g * 8;
        #pragma unroll
        for (int s = 0; s < 4; ++s) {
            float4 lo = make_float4(0.f, 0.f, 0.f, 0.f), hi = lo;
            if (avalid) {
                lo = *(const float4*)(base + s * 32);
                hi = *(const float4*)(base + s * 32 + 4);
            }
            bf16x8 v;
            v[0] = (short)f2bf(lo.x); v[1] = (short)f2bf(lo.y);
            v[2] = (short)f2bf(lo.z); v[3] = (short)f2bf(lo.w);
            v[4] = (short)f2bf(hi.x); v[5] = (short)f2bf(hi.y);
            v[6] = (short)f2bf(hi.z); v[7] = (short)f2bf(hi.w);
            af[s] = v;
        }
    }

    // ---- MFMA main loop: B-frags are wave-contiguous 1KB loads from repacked Wp ----
    f32x4 acc[8];
    #pragma unroll
    for (int t = 0; t < 8; ++t) acc[t] = (f32x4){0.f, 0.f, 0.f, 0.f};

    #pragma unroll
    for (int s = 0; s < 4; ++s) {
        bf16x8 bf[8];
        #pragma unroll
        for (int t = 0; t < 8; ++t)
            bf[t] = *(const bf16x8*)(Wp + (((size_t)(t * 4 + s) * 64) + l) * 8);
        #pragma unroll
        for (int t = 0; t < 8; ++t)
            acc[t] = __builtin_amdgcn_mfma_f32_16x16x32_bf16(af[s], bf[t], acc[t], 0, 0, 0);
    }

    // ---- + bias, per-row stats (sum / sumsq over 128 cols) ----
    float bb[8];
    #pragma unroll
    for (int t = 0; t < 8; ++t) bb[t] = bias[t * 16 + c];

    float rs[4] = {0.f, 0.f, 0.f, 0.f}, rq[4] = {0.f, 0.f, 0.f, 0.f};
    #pragma unroll
    for (int t = 0; t < 8; ++t)
        #pragma unroll
        for (int r = 0; r < 4; ++r) {
            float h = acc[t][r] + bb[t];
            acc[t][r] = h;
            rs[r] += h;
            rq[r] += h * h;
        }
    #pragma unroll
    for (int d = 1; d < 16; d <<= 1) {
        #pragma unroll
        for (int r = 0; r < 4; ++r) {
            rs[r] += __shfl_xor(rs[r], d);
            rq[r] += __shfl_xor(rq[r], d);
        }
    }
    if (c == 0) {
        #pragma unroll
        for (int r = 0; r < 4; ++r) {
            rowS[w * 16 + g * 4 + r] = rs[r];
            rowQ[w * 16 + g * 4 + r] = rq[r];
        }
    }
    __syncthreads();

    if (tid < TNODES) {
        float s = rowS[tid] + rowS[tid + 32];
        float q = rowQ[tid] + rowQ[tid + 32];
        float mean = s * (1.f / 256.f);
        float var  = q * (1.f / 256.f) - mean * mean;   // biased, torch-style
        int node = n0 + tid;
        float gam = (node < N) ? gamma[node] : 1.f;
        float bet = (node < N) ? beta[node]  : 0.f;
        float sc = gam * rsqrtf(fmaxf(var, 0.f) + 1e-5f);
        SCv[tid] = sc;
        SHv[tid] = bet - mean * sc;
    }
    __syncthreads();

    // ---- BN + GELU -> bf16 into LDS ----
    #pragma unroll
    for (int r = 0; r < 4; ++r) {
        int dr = w * 16 + g * 4 + r;
        float sc = SCv[dr & 31], sh = SHv[dr & 31];
        #pragma unroll
        for (int t = 0; t < 8; ++t) {
            float y = acc[t][r] * sc + sh;
            T[dr][t * 16 + c] = f2bf(gelu_f(y));
        }
    }
    __syncthreads();

    // ---- coalesced store: each thread emits 16B per chunk, 4 chunks ----
    #pragma unroll
    for (int q = 0; q < 4; ++q) {
        int chunk = q * 256 + tid;
        int rowi = chunk >> 4;            // 0..63
        int offc = (chunk & 15) * 8;      // u16 offset, 16B-granular
        int dn = rowi & 31, db = rowi >> 5;
        int node = n0 + dn;
        if (node < N) {
            bf16x4 lo = *(const bf16x4*)&T[rowi][offc];
            bf16x4 hi = *(const bf16x4*)&T[rowi][offc + 4];
            bf16x8 v;
            v[0] = lo[0]; v[1] = lo[1]; v[2] = lo[2]; v[3] = lo[3];
            v[4] = hi[0]; v[5] = hi[1]; v[6] = hi[2]; v[7] = hi[3];
            *(bf16x8*)(Out + ((size_t)db * N + node) * CC + offc) = v;
        }
    }
}

// ---------------- per-dst aggregation (no atomics) ----------------
// Out[b,n,c] = sum_j w_j * A[b, col_j, c].  1 wave/node; lane = (batch, 4 ch).
// Edge loop unrolled x4 for memory-level parallelism.
template<int OUT_F32>
__global__ __launch_bounds__(256) void k_aggregate(
    const u16* __restrict__ A, const int* __restrict__ off,
    const int2* __restrict__ eg, void* __restrict__ Outv, int N)
{
    int n = blockIdx.x * 4 + (threadIdx.x >> 6);
    if (n >= N) return;
    int l = threadIdx.x & 63;
    int b = l >> 5;
    int ch = (l & 31) * 4;
    const u16* Ab = A + (size_t)b * N * CC + ch;
    int s = off[n], e = off[n + 1];
    float a0 = 0.f, a1 = 0.f, a2 = 0.f, a3 = 0.f;
    int j = s;
    for (; j + 4 <= e; j += 4) {
        int2 e0 = eg[j], e1 = eg[j + 1], e2 = eg[j + 2], e3 = eg[j + 3];
        bf16x4 v0 = *(const bf16x4*)(Ab + (size_t)e0.x * CC);
        bf16x4 v1 = *(const bf16x4*)(Ab + (size_t)e1.x * CC);
        bf16x4 v2 = *(const bf16x4*)(Ab + (size_t)e2.x * CC);
        bf16x4 v3 = *(const bf16x4*)(Ab + (size_t)e3.x * CC);
        float w0 = __int_as_float(e0.y), w1 = __int_as_float(e1.y);
        float w2 = __int_as_float(e2.y), w3 = __int_as_float(e3.y);
        a0 = fmaf(w0, bf2f((u16)v0[0]), a0); a1 = fmaf(w0, bf2f((u16)v0[1]), a1);
        a2 = fmaf(w0, bf2f((u16)v0[2]), a2); a3 = fmaf(w0, bf2f((u16)v0[3]), a3);
        a0 = fmaf(w1, bf2f((u16)v1[0]), a0); a1 = fmaf(w1, bf2f((u16)v1[1]), a1);
        a2 = fmaf(w1, bf2f((u16)v1[2]), a2); a3 = fmaf(w1, bf2f((u16)v1[3]), a3);
        a0 = fmaf(w2, bf2f((u16)v2[0]), a0); a1 = fmaf(w2, bf2f((u16)v2[1]), a1);
        a2 = fmaf(w2, bf2f((u16)v2[2]), a2); a3 = fmaf(w2, bf2f((u16)v2[3]), a3);
        a0 = fmaf(w3, bf2f((u16)v3[0]), a0); a1 = fmaf(w3, bf2f((u16)v3[1]), a1);
        a2 = fmaf(w3, bf2f((u16)v3[2]), a2); a3 = fmaf(w3, bf2f((u16)v3[3]), a3);
    }
    for (; j < e; ++j) {
        int2 e0 = eg[j];
        float wt = __int_as_float(e0.y);
        bf16x4 v = *(const bf16x4*)(Ab + (size_t)e0.x * CC);
        a0 = fmaf(wt, bf2f((u16)v[0]), a0);
        a1 = fmaf(wt, bf2f((u16)v[1]), a1);
        a2 = fmaf(wt, bf2f((u16)v[2]), a2);
        a3 = fmaf(wt, bf2f((u16)v[3]), a3);
    }
    if (OUT_F32) {
        float* d = (float*)Outv + (size_t)b * N * CC + (size_t)n * CC + ch;
        d[0] = a0; d[1] = a1; d[2] = a2; d[3] = a3;
    } else {
        u16* d = (u16*)Outv + (size_t)b * N * CC + (size_t)n * CC + ch;
        bf16x4 v;
        v[0] = (short)f2bf(a0); v[1] = (short)f2bf(a1);
        v[2] = (short)f2bf(a2); v[3] = (short)f2bf(a3);
        *(bf16x4*)d = v;
    }
}

// ---------------- launch ----------------

extern "C" void kernel_launch(void* const* d_in, const int* in_sizes, int n_in,
                              void* d_out, int out_size, void* d_ws, size_t ws_size,
                              hipStream_t stream)
{
    const float* x   = (const float*)d_in[0];
    const int*   ei  = (const int*)d_in[1];
    const float* nrm = (const float*)d_in[2];
    const float* W1  = (const float*)d_in[3];
    const float* b1  = (const float*)d_in[4];
    const float* g1  = (const float*)d_in[5];
    const float* be1 = (const float*)d_in[6];
    const float* W2  = (const float*)d_in[7];
    const float* b2  = (const float*)d_in[8];
    const float* g2  = (const float*)d_in[9];
    const float* be2 = (const float*)d_in[10];

    const int N = in_sizes[5];   // g1 has N elements
    const int E = in_sizes[2];   // norm has E elements
    const int* row = ei;         // edge_index[0] = scatter dst
    const int* col = ei + E;     // edge_index[1] = gather src
    const int nb = (N + 1023) / 1024;

    auto al = [](size_t v) { return (v + 255) & ~(size_t)255; };
    char* p = (char*)d_ws;
    int* off    = (int*)p;   p += al((size_t)(N + 1) * 4);
    int* cur    = (int*)p;   p += al((size_t)N * 4);
    int2* eg    = (int2*)p;  p += al((size_t)E * 8);
    int* bsum   = (int*)p;   p += al((size_t)nb * 4);
    int* boff   = (int*)p;   p += al((size_t)nb * 4);
    u16* Wp1    = (u16*)p;   p += al((size_t)CC * CC * 2);
    u16* Wp2    = (u16*)p;   p += al((size_t)CC * CC * 2);
    u16* bufA   = (u16*)p;   p += al((size_t)2 * N * CC * 2);
    u16* bufB   = (u16*)p;   p += al((size_t)2 * N * CC * 2);

    // CSR by destination (rebuilt every call; deterministic work)
    k_zero_i32<<<(N + 255) / 256, 256, 0, stream>>>(cur, N);
    k_hist<<<(E + 255) / 256, 256, 0, stream>>>(row, cur, E);
    k_scan_a<<<nb, 256, 0, stream>>>(cur, bsum, N);
    k_scan_b<<<1, 64, 0, stream>>>(bsum, boff, off, N, nb);
    k_scan_c<<<nb, 256, 0, stream>>>(cur, boff, off, N);   // also zeroes cur
    k_fill<<<(E + 255) / 256, 256, 0, stream>>>(row, col, nrm, off, cur, eg, E);

    // W -> bf16 fragment-order repack (both layers, one launch)
    k_wrepack<<<(2 * CC * CC + 255) / 256, 256, 0, stream>>>(W1, Wp1, W2, Wp2);

    const int gb = (N + TNODES - 1) / TNODES;
    const int ga = (N + 3) / 4;
    // layer 1
    k_gemm_bn_gelu<0><<<gb, 256, 0, stream>>>(x, Wp1, b1, g1, be1, bufA, N);
    k_aggregate<0><<<ga, 256, 0, stream>>>(bufA, off, eg, bufB, N);
    // layer 2
    k_gemm_bn_gelu<1><<<gb, 256, 0, stream>>>(bufB, Wp2, b2, g2, be2, bufA, N);
    k_aggregate<1><<<ga, 256, 0, stream>>>(bufA, off, eg, (float*)d_out, N);
}

// Round 5
// 176.982 us; speedup vs baseline: 1.8726x; 1.0040x over previous
//
#include <hip/hip_runtime.h>
#include <math.h>

#define CC 128      // channels (FIN=HID=OUT)
#define TPAD 132    // LDS transpose row stride (u16): 264B, 8B-aligned, 2-way-free banks

typedef unsigned short u16;
typedef short bf16x8 __attribute__((ext_vector_type(8)));
typedef short bf16x4 __attribute__((ext_vector_type(4)));
typedef float f32x4 __attribute__((ext_vector_type(4)));

__device__ __forceinline__ u16 f2bf(float f) {
    union { float f; unsigned u; } v; v.f = f;
    unsigned u = v.u;
    return (u16)((u + 0x7FFFu + ((u >> 16) & 1u)) >> 16);   // RNE
}
__device__ __forceinline__ float bf2f(unsigned hi16) {
    union { unsigned u; float f; } v; v.u = hi16 << 16; return v.f;
}

// Exact-GELU via branch-free A&S 7.1.26 erf (|err| < 1.5e-7, far below bf16 noise).
__device__ __forceinline__ float gelu_f(float y) {
    float xa = fabsf(y) * 0.70710678118654752f;
    float t  = __builtin_amdgcn_rcpf(fmaf(0.3275911f, xa, 1.0f));
    float p  = fmaf(1.061405429f, t, -1.453152027f);
    p = fmaf(p, t, 1.421413741f);
    p = fmaf(p, t, -0.284496736f);
    p = fmaf(p, t, 0.254829592f);
    p *= t;
    float e  = __expf(-xa * xa);
    float er = fmaf(-p, e, 1.0f);          // erf(|x|)
    float s  = copysignf(er, y);
    return 0.5f * y * (1.0f + s);
}

// ---------------- CSR build ----------------

__global__ __launch_bounds__(256) void k_zero_i32(int* __restrict__ p, int n) {
    int i = blockIdx.x * 256 + threadIdx.x;
    if (i < n) p[i] = 0;
}

__global__ __launch_bounds__(256) void k_hist(const int* __restrict__ row, int* __restrict__ cnt, int E) {
    int e = blockIdx.x * 256 + threadIdx.x;
    if (e < E) atomicAdd(&cnt[row[e]], 1);
}

__device__ __forceinline__ int wave_incl_scan(int v) {
    #pragma unroll
    for (int d = 1; d < 64; d <<= 1) {
        int t = __shfl_up(v, d);
        if ((threadIdx.x & 63) >= d) v += t;
    }
    return v;
}

__global__ __launch_bounds__(256) void k_scan_a(const int* __restrict__ cnt, int* __restrict__ bsum, int N) {
    int base = blockIdx.x * 1024 + threadIdx.x * 4;
    int s = 0;
    #pragma unroll
    for (int u = 0; u < 4; ++u) { int i = base + u; if (i < N) s += cnt[i]; }
    #pragma unroll
    for (int d = 32; d > 0; d >>= 1) s += __shfl_down(s, d);
    __shared__ int wsum[4];
    if ((threadIdx.x & 63) == 0) wsum[threadIdx.x >> 6] = s;
    __syncthreads();
    if (threadIdx.x == 0) bsum[blockIdx.x] = wsum[0] + wsum[1] + wsum[2] + wsum[3];
}

__global__ __launch_bounds__(64) void k_scan_b(const int* __restrict__ bsum, int* __restrict__ boff,
                                               int* __restrict__ off, int N, int nb) {
    int carry = 0;
    for (int base = 0; base < nb; base += 64) {
        int t = base + (int)threadIdx.x;
        int v = (t < nb) ? bsum[t] : 0;
        int incl = wave_incl_scan(v);
        if (t < nb) boff[t] = carry + incl - v;
        carry += __shfl(incl, 63);
    }
    if (threadIdx.x == 0) off[N] = carry;
}

// local scan + global offset -> off[i]; also zeroes cnt for the subsequent k_fill
__global__ __launch_bounds__(256) void k_scan_c(int* __restrict__ cnt, const int* __restrict__ boff,
                                                int* __restrict__ off, int N) {
    int t = threadIdx.x;
    int base = blockIdx.x * 1024 + t * 4;
    int v[4]; int s = 0;
    #pragma unroll
    for (int u = 0; u < 4; ++u) { int i = base + u; v[u] = (i < N) ? cnt[i] : 0; s += v[u]; }
    int incl = wave_incl_scan(s);
    __shared__ int wsum[4];
    int w = t >> 6, lane = t & 63;
    if (lane == 63) wsum[w] = incl;
    __syncthreads();
    int run = incl - s + boff[blockIdx.x];
    for (int ww = 0; ww < w; ++ww) run += wsum[ww];
    #pragma unroll
    for (int u = 0; u < 4; ++u) {
        int i = base + u;
        if (i < N) { off[i] = run; cnt[i] = 0; }
        run += v[u];
    }
}

// packed edge list: .x = src col, .y = weight bits
__global__ __launch_bounds__(256) void k_fill(const int* __restrict__ row, const int* __restrict__ col,
                                              const float* __restrict__ nrm, const int* __restrict__ off,
                                              int* __restrict__ cur, int2* __restrict__ eg, int E) {
    int e = blockIdx.x * 256 + threadIdx.x;
    if (e < E) {
        int r = row[e];
        int p = off[r] + atomicAdd(&cur[r], 1);
        eg[p] = make_int2(col[e], __float_as_int(nrm[e]));
    }
}

// ---------------- W1,W2 -> bf16, repacked into MFMA B-fragment order ----------------
// Wp[((t*4+s)*64 + l)*8 + j] = bf16( W[16t + (l&15)][s*32 + (l>>4)*8 + j] )
__global__ __launch_bounds__(256) void k_wrepack(const float* __restrict__ W1, u16* __restrict__ Wp1,
                                                 const float* __restrict__ W2, u16* __restrict__ Wp2) {
    int i = blockIdx.x * 256 + threadIdx.x;
    const float* W = (i < CC * CC) ? W1 : W2;
    u16* Wp = (i < CC * CC) ? Wp1 : Wp2;
    int ii = (i < CC * CC) ? i : i - CC * CC;
    if (ii < CC * CC) {
        int j = ii & 7, l = (ii >> 3) & 63, s = (ii >> 9) & 3, t = ii >> 11;
        int r = 16 * t + (l & 15);
        int k = s * 32 + (l >> 4) * 8 + j;
        Wp[ii] = f2bf(W[r * CC + k]);
    }
}

// ---------------- fused MFMA GEMM + BatchNorm + GELU (wave-independent) ----------------
// Each wave owns 8 nodes: 16 M-rows (rows 0..7 = batch0, 8..15 = batch1 of nodes n8..n8+7).
// BN stats are fully in-register: shfl_xor over the 16-lane col group + shfl_xor(32) to
// merge the batch halves. No cross-wave coupling; single barrier for the store transpose.
template<int IN_BF16>
__global__ __launch_bounds__(256) void k_gemm_bn_gelu(
    const void* __restrict__ Xv, const u16* __restrict__ Wp,
    const float* __restrict__ bias, const float* __restrict__ gamma, const float* __restrict__ beta,
    u16* __restrict__ Out, int N)
{
    __shared__ u16 T[4][16][TPAD];

    const int tid = threadIdx.x;
    const int w = tid >> 6;
    const int l = tid & 63;
    const int g = l >> 4;
    const int c = l & 15;
    const int n8 = blockIdx.x * 32 + w * 8;
    const bool valid = n8 < N;          // uniform across the wave (N % 8 == 0 handled by guard)
    const int nbase = valid ? n8 : 0;

    // ---- A fragment: lane row = c -> (batch = c>>3, node = nbase + (c&7)) ----
    const int ab = c >> 3;
    const int an = nbase + (c & 7);

    bf16x8 af[4];
    if (IN_BF16) {
        const u16* X = (const u16*)Xv;
        const u16* base = X + ((size_t)ab * N + an) * CC + g * 8;
        #pragma unroll
        for (int s = 0; s < 4; ++s) af[s] = *(const bf16x8*)(base + s * 32);
    } else {
        const float* X = (const float*)Xv;
        const float* base = X + ((size_t)ab * N + an) * CC + g * 8;
        #pragma unroll
        for (int s = 0; s < 4; ++s) {
            float4 lo = *(const float4*)(base + s * 32);
            float4 hi = *(const float4*)(base + s * 32 + 4);
            bf16x8 v;
            v[0] = (short)f2bf(lo.x); v[1] = (short)f2bf(lo.y);
            v[2] = (short)f2bf(lo.z); v[3] = (short)f2bf(lo.w);
            v[4] = (short)f2bf(hi.x); v[5] = (short)f2bf(hi.y);
            v[6] = (short)f2bf(hi.z); v[7] = (short)f2bf(hi.w);
            af[s] = v;
        }
    }

    // ---- MFMA: 8 col-tiles x 4 K-steps; B-frags are wave-contiguous 1KB loads ----
    f32x4 acc[8];
    #pragma unroll
    for (int t = 0; t < 8; ++t) acc[t] = (f32x4){0.f, 0.f, 0.f, 0.f};

    #pragma unroll
    for (int s = 0; s < 4; ++s) {
        bf16x8 bf[8];
        #pragma unroll
        for (int t = 0; t < 8; ++t)
            bf[t] = *(const bf16x8*)(Wp + (((size_t)(t * 4 + s) * 64) + l) * 8);
        #pragma unroll
        for (int t = 0; t < 8; ++t)
            acc[t] = __builtin_amdgcn_mfma_f32_16x16x32_bf16(af[s], bf[t], acc[t], 0, 0, 0);
    }

    // ---- + bias, per-row partial stats ----
    float bb[8];
    #pragma unroll
    for (int t = 0; t < 8; ++t) bb[t] = bias[t * 16 + c];

    float rs[4] = {0.f, 0.f, 0.f, 0.f}, rq[4] = {0.f, 0.f, 0.f, 0.f};
    #pragma unroll
    for (int t = 0; t < 8; ++t)
        #pragma unroll
        for (int r = 0; r < 4; ++r) {
            float h = acc[t][r] + bb[t];
            acc[t][r] = h;
            rs[r] += h;
            rq[r] += h * h;
        }
    // reduce over the 16 col-lanes, then merge batch halves (row <-> row±8 is lane^32)
    #pragma unroll
    for (int d = 1; d < 16; d <<= 1) {
        #pragma unroll
        for (int r = 0; r < 4; ++r) {
            rs[r] += __shfl_xor(rs[r], d);
            rq[r] += __shfl_xor(rq[r], d);
        }
    }
    #pragma unroll
    for (int r = 0; r < 4; ++r) {
        rs[r] += __shfl_xor(rs[r], 32);
        rq[r] += __shfl_xor(rq[r], 32);
    }

    // ---- per-node BN params (node p = (4g+r) & 7), fully in-register ----
    float sc[4], sh[4];
    #pragma unroll
    for (int r = 0; r < 4; ++r) {
        int p = (4 * g + r) & 7;
        int node = nbase + p;
        float mean = rs[r] * (1.f / 256.f);
        float var  = rq[r] * (1.f / 256.f) - mean * mean;   // biased, torch-style
        float gam = gamma[node];
        float bet = beta[node];
        float s_ = gam * rsqrtf(fmaxf(var, 0.f) + 1e-5f);
        sc[r] = s_;
        sh[r] = bet - mean * s_;
    }

    // ---- BN + GELU -> bf16 into this wave's LDS tile ----
    #pragma unroll
    for (int r = 0; r < 4; ++r) {
        int row = 4 * g + r;
        #pragma unroll
        for (int t = 0; t < 8; ++t) {
            float y = acc[t][r] * sc[r] + sh[r];
            T[w][row][t * 16 + c] = f2bf(gelu_f(y));
        }
    }
    __syncthreads();

    // ---- coalesced store: 4 iters x 64 lanes x 16B = 4KB per wave ----
    if (valid) {
        #pragma unroll
        for (int it = 0; it < 4; ++it) {
            int chunk = it * 64 + l;
            int rowi = chunk >> 4;            // 0..15
            int offc = (chunk & 15) * 8;      // u16 offset
            int db = rowi >> 3;
            int dn = n8 + (rowi & 7);
            bf16x4 lo = *(const bf16x4*)&T[w][rowi][offc];
            bf16x4 hi = *(const bf16x4*)&T[w][rowi][offc + 4];
            bf16x8 v;
            v[0] = lo[0]; v[1] = lo[1]; v[2] = lo[2]; v[3] = lo[3];
            v[4] = hi[0]; v[5] = hi[1]; v[6] = hi[2]; v[7] = hi[3];
            *(bf16x8*)(Out + ((size_t)db * N + dn) * CC + offc) = v;
        }
    }
}

// ---------------- per-dst aggregation (no atomics) ----------------
// 1 wave/node, 2 edges in parallel: lane = (parity = l>>5, batch = (l>>4)&1, 8 ch).
// One bf16x8 (16B) load per lane -> 1KB per instruction; parity merged by shfl_xor(32).
template<int OUT_F32>
__global__ __launch_bounds__(256) void k_aggregate(
    const u16* __restrict__ A, const int* __restrict__ off,
    const int2* __restrict__ eg, void* __restrict__ Outv, int N)
{
    int n = blockIdx.x * 4 + (threadIdx.x >> 6);
    if (n >= N) return;
    int l = threadIdx.x & 63;
    int p = l >> 5;
    int b = (l >> 4) & 1;
    int ch0 = (l & 15) * 8;
    const u16* Ab = A + (size_t)b * N * CC + ch0;
    int s = off[n], e = off[n + 1];
    float a[8] = {0.f, 0.f, 0.f, 0.f, 0.f, 0.f, 0.f, 0.f};
    for (int j = s; j < e; j += 4) {
        int i0 = j + p, i1 = j + 2 + p;
        int2 e0 = (i0 < e) ? eg[i0] : make_int2(0, 0);
        int2 e1 = (i1 < e) ? eg[i1] : make_int2(0, 0);
        bf16x8 v0 = *(const bf16x8*)(Ab + (size_t)e0.x * CC);
        bf16x8 v1 = *(const bf16x8*)(Ab + (size_t)e1.x * CC);
        float w0 = __int_as_float(e0.y), w1 = __int_as_float(e1.y);
        #pragma unroll
        for (int q = 0; q < 8; ++q) {
            a[q] = fmaf(w0, bf2f((u16)v0[q]), a[q]);
            a[q] = fmaf(w1, bf2f((u16)v1[q]), a[q]);
        }
    }
    #pragma unroll
    for (int q = 0; q < 8; ++q) a[q] += __shfl_xor(a[q], 32);
    if (l < 32) {
        if (OUT_F32) {
            float* d = (float*)Outv + ((size_t)b * N + n) * CC + ch0;
            *(float4*)&d[0] = make_float4(a[0], a[1], a[2], a[3]);
            *(float4*)&d[4] = make_float4(a[4], a[5], a[6], a[7]);
        } else {
            u16* d = (u16*)Outv + ((size_t)b * N + n) * CC + ch0;
            bf16x8 v;
            #pragma unroll
            for (int q = 0; q < 8; ++q) v[q] = (short)f2bf(a[q]);
            *(bf16x8*)d = v;
        }
    }
}

// ---------------- launch ----------------

extern "C" void kernel_launch(void* const* d_in, const int* in_sizes, int n_in,
                              void* d_out, int out_size, void* d_ws, size_t ws_size,
                              hipStream_t stream)
{
    const float* x   = (const float*)d_in[0];
    const int*   ei  = (const int*)d_in[1];
    const float* nrm = (const float*)d_in[2];
    const float* W1  = (const float*)d_in[3];
    const float* b1  = (const float*)d_in[4];
    const float* g1  = (const float*)d_in[5];
    const float* be1 = (const float*)d_in[6];
    const float* W2  = (const float*)d_in[7];
    const float* b2  = (const float*)d_in[8];
    const float* g2  = (const float*)d_in[9];
    const float* be2 = (const float*)d_in[10];

    const int N = in_sizes[5];   // g1 has N elements
    const int E = in_sizes[2];   // norm has E elements
    const int* row = ei;         // edge_index[0] = scatter dst
    const int* col = ei + E;     // edge_index[1] = gather src
    const int nb = (N + 1023) / 1024;

    auto al = [](size_t v) { return (v + 255) & ~(size_t)255; };
    char* p = (char*)d_ws;
    int* off    = (int*)p;   p += al((size_t)(N + 1) * 4);
    int* cur    = (int*)p;   p += al((size_t)N * 4);
    int2* eg    = (int2*)p;  p += al((size_t)E * 8);
    int* bsum   = (int*)p;   p += al((size_t)nb * 4);
    int* boff   = (int*)p;   p += al((size_t)nb * 4);
    u16* Wp1    = (u16*)p;   p += al((size_t)CC * CC * 2);
    u16* Wp2    = (u16*)p;   p += al((size_t)CC * CC * 2);
    u16* bufA   = (u16*)p;   p += al((size_t)2 * N * CC * 2);
    u16* bufB   = (u16*)p;   p += al((size_t)2 * N * CC * 2);

    // CSR by destination (rebuilt every call; deterministic work)
    k_zero_i32<<<(N + 255) / 256, 256, 0, stream>>>(cur, N);
    k_hist<<<(E + 255) / 256, 256, 0, stream>>>(row, cur, E);
    k_scan_a<<<nb, 256, 0, stream>>>(cur, bsum, N);
    k_scan_b<<<1, 64, 0, stream>>>(bsum, boff, off, N, nb);
    k_scan_c<<<nb, 256, 0, stream>>>(cur, boff, off, N);   // also zeroes cur
    k_fill<<<(E + 255) / 256, 256, 0, stream>>>(row, col, nrm, off, cur, eg, E);

    // W -> bf16 fragment-order repack (both layers, one launch)
    k_wrepack<<<(2 * CC * CC + 255) / 256, 256, 0, stream>>>(W1, Wp1, W2, Wp2);

    const int gb = (N + 31) / 32;
    const int ga = (N + 3) / 4;
    // layer 1
    k_gemm_bn_gelu<0><<<gb, 256, 0, stream>>>(x, Wp1, b1, g1, be1, bufA, N);
    k_aggregate<0><<<ga, 256, 0, stream>>>(bufA, off, eg, bufB, N);
    // layer 2
    k_gemm_bn_gelu<1><<<gb, 256, 0, stream>>>(bufB, Wp2, b2, g2, be2, bufA, N);
    k_aggregate<1><<<ga, 256, 0, stream>>>(bufA, off, eg, (float*)d_out, N);
}

// Round 6
// 174.855 us; speedup vs baseline: 1.8954x; 1.0122x over previous
//
#include <hip/hip_runtime.h>
#include <math.h>

#define CC 128      // channels (FIN=HID=OUT)
#define TPAD 132    // LDS transpose row stride (u16): 264B, 8B-aligned, 2-way-free banks

typedef unsigned short u16;
typedef short bf16x8 __attribute__((ext_vector_type(8)));
typedef short bf16x4 __attribute__((ext_vector_type(4)));
typedef float f32x4 __attribute__((ext_vector_type(4)));

__device__ __forceinline__ u16 f2bf(float f) {
    union { float f; unsigned u; } v; v.f = f;
    unsigned u = v.u;
    return (u16)((u + 0x7FFFu + ((u >> 16) & 1u)) >> 16);   // RNE
}
__device__ __forceinline__ float bf2f(unsigned hi16) {
    union { unsigned u; float f; } v; v.u = hi16 << 16; return v.f;
}

// Exact-GELU via branch-free A&S 7.1.26 erf (|err| < 1.5e-7, far below bf16 noise).
__device__ __forceinline__ float gelu_f(float y) {
    float xa = fabsf(y) * 0.70710678118654752f;
    float t  = __builtin_amdgcn_rcpf(fmaf(0.3275911f, xa, 1.0f));
    float p  = fmaf(1.061405429f, t, -1.453152027f);
    p = fmaf(p, t, 1.421413741f);
    p = fmaf(p, t, -0.284496736f);
    p = fmaf(p, t, 0.254829592f);
    p *= t;
    float e  = __expf(-xa * xa);
    float er = fmaf(-p, e, 1.0f);          // erf(|x|)
    float s  = copysignf(er, y);
    return 0.5f * y * (1.0f + s);
}

// ---------------- CSR build ----------------

__global__ __launch_bounds__(256) void k_zero_i32(int* __restrict__ p, int n) {
    int i = blockIdx.x * 256 + threadIdx.x;
    if (i < n) p[i] = 0;
}

__global__ __launch_bounds__(256) void k_hist(const int* __restrict__ row, int* __restrict__ cnt, int E) {
    int e = blockIdx.x * 256 + threadIdx.x;
    if (e < E) atomicAdd(&cnt[row[e]], 1);
}

__device__ __forceinline__ int wave_incl_scan(int v) {
    #pragma unroll
    for (int d = 1; d < 64; d <<= 1) {
        int t = __shfl_up(v, d);
        if ((threadIdx.x & 63) >= d) v += t;
    }
    return v;
}

__global__ __launch_bounds__(256) void k_scan_a(const int* __restrict__ cnt, int* __restrict__ bsum, int N) {
    int base = blockIdx.x * 1024 + threadIdx.x * 4;
    int s = 0;
    #pragma unroll
    for (int u = 0; u < 4; ++u) { int i = base + u; if (i < N) s += cnt[i]; }
    #pragma unroll
    for (int d = 32; d > 0; d >>= 1) s += __shfl_down(s, d);
    __shared__ int wsum[4];
    if ((threadIdx.x & 63) == 0) wsum[threadIdx.x >> 6] = s;
    __syncthreads();
    if (threadIdx.x == 0) bsum[blockIdx.x] = wsum[0] + wsum[1] + wsum[2] + wsum[3];
}

__global__ __launch_bounds__(64) void k_scan_b(const int* __restrict__ bsum, int* __restrict__ boff,
                                               int* __restrict__ off, int N, int nb) {
    int carry = 0;
    for (int base = 0; base < nb; base += 64) {
        int t = base + (int)threadIdx.x;
        int v = (t < nb) ? bsum[t] : 0;
        int incl = wave_incl_scan(v);
        if (t < nb) boff[t] = carry + incl - v;
        carry += __shfl(incl, 63);
    }
    if (threadIdx.x == 0) off[N] = carry;
}

// local scan + global offset -> off[i]; also zeroes cnt for the subsequent k_fill
__global__ __launch_bounds__(256) void k_scan_c(int* __restrict__ cnt, const int* __restrict__ boff,
                                                int* __restrict__ off, int N) {
    int t = threadIdx.x;
    int base = blockIdx.x * 1024 + t * 4;
    int v[4]; int s = 0;
    #pragma unroll
    for (int u = 0; u < 4; ++u) { int i = base + u; v[u] = (i < N) ? cnt[i] : 0; s += v[u]; }
    int incl = wave_incl_scan(s);
    __shared__ int wsum[4];
    int w = t >> 6, lane = t & 63;
    if (lane == 63) wsum[w] = incl;
    __syncthreads();
    int run = incl - s + boff[blockIdx.x];
    for (int ww = 0; ww < w; ++ww) run += wsum[ww];
    #pragma unroll
    for (int u = 0; u < 4; ++u) {
        int i = base + u;
        if (i < N) { off[i] = run; cnt[i] = 0; }
        run += v[u];
    }
}

// packed edge list: .x = src col, .y = weight bits
__global__ __launch_bounds__(256) void k_fill(const int* __restrict__ row, const int* __restrict__ col,
                                              const float* __restrict__ nrm, const int* __restrict__ off,
                                              int* __restrict__ cur, int2* __restrict__ eg, int E) {
    int e = blockIdx.x * 256 + threadIdx.x;
    if (e < E) {
        int r = row[e];
        int p = off[r] + atomicAdd(&cur[r], 1);
        eg[p] = make_int2(col[e], __float_as_int(nrm[e]));
    }
}

// ---------------- W1,W2 -> bf16, repacked into MFMA B-fragment order ----------------
// Wp[((t*4+s)*64 + l)*8 + j] = bf16( W[16t + (l&15)][s*32 + (l>>4)*8 + j] )
__global__ __launch_bounds__(256) void k_wrepack(const float* __restrict__ W1, u16* __restrict__ Wp1,
                                                 const float* __restrict__ W2, u16* __restrict__ Wp2) {
    int i = blockIdx.x * 256 + threadIdx.x;
    const float* W = (i < CC * CC) ? W1 : W2;
    u16* Wp = (i < CC * CC) ? Wp1 : Wp2;
    int ii = (i < CC * CC) ? i : i - CC * CC;
    if (ii < CC * CC) {
        int j = ii & 7, l = (ii >> 3) & 63, s = (ii >> 9) & 3, t = ii >> 11;
        int r = 16 * t + (l & 15);
        int k = s * 32 + (l >> 4) * 8 + j;
        Wp[ii] = f2bf(W[r * CC + k]);
    }
}

// ---------------- fused MFMA GEMM + BatchNorm + GELU (register-resident B) ----------------
// Each wave owns 8 nodes: 16 M-rows (rows 0..7 = batch0, 8..15 = batch1 of nodes n8..n8+7).
// ALL 32 B-fragments (the whole 128x128 W) are loaded into registers up-front (128 VGPRs,
// one vmcnt window, 32 loads in flight) so the 32 MFMAs run back-to-back with zero memory
// dependencies. __launch_bounds__(256,1) gives the register allocator room (~200 VGPRs);
// 2 waves/SIMD is plenty since the kernel is now issue-dense, not latency-exposed.
template<int IN_BF16>
__global__ __launch_bounds__(256, 1) void k_gemm_bn_gelu(
    const void* __restrict__ Xv, const u16* __restrict__ Wp,
    const float* __restrict__ bias, const float* __restrict__ gamma, const float* __restrict__ beta,
    u16* __restrict__ Out, int N)
{
    __shared__ u16 T[4][16][TPAD];

    const int tid = threadIdx.x;
    const int w = tid >> 6;
    const int l = tid & 63;
    const int g = l >> 4;
    const int c = l & 15;
    const int n8 = blockIdx.x * 32 + w * 8;
    const bool valid = n8 < N;          // uniform across the wave (N % 8 == 0)
    const int nbase = valid ? n8 : 0;

    // ---- ALL B fragments -> registers (32 x bf16x8 = 128 VGPRs), independent loads ----
    bf16x8 B[32];
    #pragma unroll
    for (int i = 0; i < 32; ++i)
        B[i] = *(const bf16x8*)(Wp + ((size_t)i * 64 + l) * 8);

    // ---- A fragment: lane row = c -> (batch = c>>3, node = nbase + (c&7)) ----
    const int ab = c >> 3;
    const int an = nbase + (c & 7);

    bf16x8 af[4];
    if (IN_BF16) {
        const u16* X = (const u16*)Xv;
        const u16* base = X + ((size_t)ab * N + an) * CC + g * 8;
        #pragma unroll
        for (int s = 0; s < 4; ++s) af[s] = *(const bf16x8*)(base + s * 32);
    } else {
        const float* X = (const float*)Xv;
        const float* base = X + ((size_t)ab * N + an) * CC + g * 8;
        float4 lo[4], hi[4];
        #pragma unroll
        for (int s = 0; s < 4; ++s) {
            lo[s] = *(const float4*)(base + s * 32);
            hi[s] = *(const float4*)(base + s * 32 + 4);
        }
        #pragma unroll
        for (int s = 0; s < 4; ++s) {
            bf16x8 v;
            v[0] = (short)f2bf(lo[s].x); v[1] = (short)f2bf(lo[s].y);
            v[2] = (short)f2bf(lo[s].z); v[3] = (short)f2bf(lo[s].w);
            v[4] = (short)f2bf(hi[s].x); v[5] = (short)f2bf(hi[s].y);
            v[6] = (short)f2bf(hi[s].z); v[7] = (short)f2bf(hi[s].w);
            af[s] = v;
        }
    }

    // ---- MFMA: 32 back-to-back, pure register operands ----
    f32x4 acc[8];
    #pragma unroll
    for (int t = 0; t < 8; ++t) acc[t] = (f32x4){0.f, 0.f, 0.f, 0.f};

    #pragma unroll
    for (int s = 0; s < 4; ++s)
        #pragma unroll
        for (int t = 0; t < 8; ++t)
            acc[t] = __builtin_amdgcn_mfma_f32_16x16x32_bf16(af[s], B[t * 4 + s], acc[t], 0, 0, 0);

    // ---- + bias, per-row partial stats ----
    float bb[8];
    #pragma unroll
    for (int t = 0; t < 8; ++t) bb[t] = bias[t * 16 + c];

    float rs[4] = {0.f, 0.f, 0.f, 0.f}, rq[4] = {0.f, 0.f, 0.f, 0.f};
    #pragma unroll
    for (int t = 0; t < 8; ++t)
        #pragma unroll
        for (int r = 0; r < 4; ++r) {
            float h = acc[t][r] + bb[t];
            acc[t][r] = h;
            rs[r] += h;
            rq[r] += h * h;
        }
    // reduce over the 16 col-lanes, then merge batch halves (row <-> row±8 is lane^32)
    #pragma unroll
    for (int d = 1; d < 16; d <<= 1) {
        #pragma unroll
        for (int r = 0; r < 4; ++r) {
            rs[r] += __shfl_xor(rs[r], d);
            rq[r] += __shfl_xor(rq[r], d);
        }
    }
    #pragma unroll
    for (int r = 0; r < 4; ++r) {
        rs[r] += __shfl_xor(rs[r], 32);
        rq[r] += __shfl_xor(rq[r], 32);
    }

    // ---- per-node BN params (node p = (4g+r) & 7), fully in-register ----
    float sc[4], sh[4];
    #pragma unroll
    for (int r = 0; r < 4; ++r) {
        int p = (4 * g + r) & 7;
        int node = nbase + p;
        float mean = rs[r] * (1.f / 256.f);
        float var  = rq[r] * (1.f / 256.f) - mean * mean;   // biased, torch-style
        float gam = gamma[node];
        float bet = beta[node];
        float s_ = gam * rsqrtf(fmaxf(var, 0.f) + 1e-5f);
        sc[r] = s_;
        sh[r] = bet - mean * s_;
    }

    // ---- BN + GELU -> bf16 into this wave's LDS tile ----
    #pragma unroll
    for (int r = 0; r < 4; ++r) {
        int row = 4 * g + r;
        #pragma unroll
        for (int t = 0; t < 8; ++t) {
            float y = acc[t][r] * sc[r] + sh[r];
            T[w][row][t * 16 + c] = f2bf(gelu_f(y));
        }
    }
    __syncthreads();

    // ---- coalesced store: 4 iters x 64 lanes x 16B = 4KB per wave ----
    if (valid) {
        #pragma unroll
        for (int it = 0; it < 4; ++it) {
            int chunk = it * 64 + l;
            int rowi = chunk >> 4;            // 0..15
            int offc = (chunk & 15) * 8;      // u16 offset
            int db = rowi >> 3;
            int dn = n8 + (rowi & 7);
            bf16x4 lo = *(const bf16x4*)&T[w][rowi][offc];
            bf16x4 hi = *(const bf16x4*)&T[w][rowi][offc + 4];
            bf16x8 v;
            v[0] = lo[0]; v[1] = lo[1]; v[2] = lo[2]; v[3] = lo[3];
            v[4] = hi[0]; v[5] = hi[1]; v[6] = hi[2]; v[7] = hi[3];
            *(bf16x8*)(Out + ((size_t)db * N + dn) * CC + offc) = v;
        }
    }
}

// ---------------- per-dst aggregation (no atomics) ----------------
// 1 wave/node, 2 edges in parallel: lane = (parity = l>>5, batch = (l>>4)&1, 8 ch).
// One bf16x8 (16B) load per lane -> 1KB per instruction; parity merged by shfl_xor(32).
template<int OUT_F32>
__global__ __launch_bounds__(256) void k_aggregate(
    const u16* __restrict__ A, const int* __restrict__ off,
    const int2* __restrict__ eg, void* __restrict__ Outv, int N)
{
    int n = blockIdx.x * 4 + (threadIdx.x >> 6);
    if (n >= N) return;
    int l = threadIdx.x & 63;
    int p = l >> 5;
    int b = (l >> 4) & 1;
    int ch0 = (l & 15) * 8;
    const u16* Ab = A + (size_t)b * N * CC + ch0;
    int s = off[n], e = off[n + 1];
    float a[8] = {0.f, 0.f, 0.f, 0.f, 0.f, 0.f, 0.f, 0.f};
    for (int j = s; j < e; j += 4) {
        int i0 = j + p, i1 = j + 2 + p;
        int2 e0 = (i0 < e) ? eg[i0] : make_int2(0, 0);
        int2 e1 = (i1 < e) ? eg[i1] : make_int2(0, 0);
        bf16x8 v0 = *(const bf16x8*)(Ab + (size_t)e0.x * CC);
        bf16x8 v1 = *(const bf16x8*)(Ab + (size_t)e1.x * CC);
        float w0 = __int_as_float(e0.y), w1 = __int_as_float(e1.y);
        #pragma unroll
        for (int q = 0; q < 8; ++q) {
            a[q] = fmaf(w0, bf2f((u16)v0[q]), a[q]);
            a[q] = fmaf(w1, bf2f((u16)v1[q]), a[q]);
        }
    }
    #pragma unroll
    for (int q = 0; q < 8; ++q) a[q] += __shfl_xor(a[q], 32);
    if (l < 32) {
        if (OUT_F32) {
            float* d = (float*)Outv + ((size_t)b * N + n) * CC + ch0;
            *(float4*)&d[0] = make_float4(a[0], a[1], a[2], a[3]);
            *(float4*)&d[4] = make_float4(a[4], a[5], a[6], a[7]);
        } else {
            u16* d = (u16*)Outv + ((size_t)b * N + n) * CC + ch0;
            bf16x8 v;
            #pragma unroll
            for (int q = 0; q < 8; ++q) v[q] = (short)f2bf(a[q]);
            *(bf16x8*)d = v;
        }
    }
}

// ---------------- launch ----------------

extern "C" void kernel_launch(void* const* d_in, const int* in_sizes, int n_in,
                              void* d_out, int out_size, void* d_ws, size_t ws_size,
                              hipStream_t stream)
{
    const float* x   = (const float*)d_in[0];
    const int*   ei  = (const int*)d_in[1];
    const float* nrm = (const float*)d_in[2];
    const float* W1  = (const float*)d_in[3];
    const float* b1  = (const float*)d_in[4];
    const float* g1  = (const float*)d_in[5];
    const float* be1 = (const float*)d_in[6];
    const float* W2  = (const float*)d_in[7];
    const float* b2  = (const float*)d_in[8];
    const float* g2  = (const float*)d_in[9];
    const float* be2 = (const float*)d_in[10];

    const int N = in_sizes[5];   // g1 has N elements
    const int E = in_sizes[2];   // norm has E elements
    const int* row = ei;         // edge_index[0] = scatter dst
    const int* col = ei + E;     // edge_index[1] = gather src
    const int nb = (N + 1023) / 1024;

    auto al = [](size_t v) { return (v + 255) & ~(size_t)255; };
    char* p = (char*)d_ws;
    int* off    = (int*)p;   p += al((size_t)(N + 1) * 4);
    int* cur    = (int*)p;   p += al((size_t)N * 4);
    int2* eg    = (int2*)p;  p += al((size_t)E * 8);
    int* bsum   = (int*)p;   p += al((size_t)nb * 4);
    int* boff   = (int*)p;   p += al((size_t)nb * 4);
    u16* Wp1    = (u16*)p;   p += al((size_t)CC * CC * 2);
    u16* Wp2    = (u16*)p;   p += al((size_t)CC * CC * 2);
    u16* bufA   = (u16*)p;   p += al((size_t)2 * N * CC * 2);
    u16* bufB   = (u16*)p;   p += al((size_t)2 * N * CC * 2);

    // CSR by destination (rebuilt every call; deterministic work)
    k_zero_i32<<<(N + 255) / 256, 256, 0, stream>>>(cur, N);
    k_hist<<<(E + 255) / 256, 256, 0, stream>>>(row, cur, E);
    k_scan_a<<<nb, 256, 0, stream>>>(cur, bsum, N);
    k_scan_b<<<1, 64, 0, stream>>>(bsum, boff, off, N, nb);
    k_scan_c<<<nb, 256, 0, stream>>>(cur, boff, off, N);   // also zeroes cur
    k_fill<<<(E + 255) / 256, 256, 0, stream>>>(row, col, nrm, off, cur, eg, E);

    // W -> bf16 fragment-order repack (both layers, one launch)
    k_wrepack<<<(2 * CC * CC + 255) / 256, 256, 0, stream>>>(W1, Wp1, W2, Wp2);

    const int gb = (N + 31) / 32;
    const int ga = (N + 3) / 4;
    // layer 1
    k_gemm_bn_gelu<0><<<gb, 256, 0, stream>>>(x, Wp1, b1, g1, be1, bufA, N);
    k_aggregate<0><<<ga, 256, 0, stream>>>(bufA, off, eg, bufB, N);
    // layer 2
    k_gemm_bn_gelu<1><<<gb, 256, 0, stream>>>(bufB, Wp2, b2, g2, be2, bufA, N);
    k_aggregate<1><<<ga, 256, 0, stream>>>(bufA, off, eg, (float*)d_out, N);
}